// Round 1
// baseline (336.967 us; speedup 1.0000x reference)
//
#include <hip/hip_runtime.h>
#include <math.h>

#define N_ROIS 1024
#define C_DIM  1024
#define G_DIM  16
#define PE_DIM 64
#define LROW   (G_DIM * N_ROIS)   // 16384: row stride of logits over n

// ---------------------------------------------------------------------------
// C[i,j] = dot(A[i,:], B[j,:]) + (bias ? bias[j] : 0)   (all 1024x1024, NT)
// 64x64 block tile, BK=16, 256 threads, 4x4 micro-tile per thread.
// ---------------------------------------------------------------------------
__global__ __launch_bounds__(256) void gemm_nt_bias(const float* __restrict__ A,
                                                    const float* __restrict__ B,
                                                    const float* __restrict__ bias,
                                                    float* __restrict__ C)
{
    constexpr int LDT = 68;                 // 64 + 4 pad, keeps float4 alignment
    __shared__ float As[16 * LDT];          // As[kk][i]
    __shared__ float Bs[16 * LDT];          // Bs[kk][j]
    const int t  = threadIdx.x;
    const int bi = blockIdx.y * 64;
    const int bj = blockIdx.x * 64;
    const int tx = t & 15, ty = t >> 4;
    const int lrow = t >> 2, lk = (t & 3) * 4;
    float acc[4][4] = {};
    for (int k0 = 0; k0 < C_DIM; k0 += 16) {
        float4 av = *(const float4*)&A[(bi + lrow) * C_DIM + k0 + lk];
        float4 bv = *(const float4*)&B[(bj + lrow) * C_DIM + k0 + lk];
        As[(lk + 0) * LDT + lrow] = av.x;
        As[(lk + 1) * LDT + lrow] = av.y;
        As[(lk + 2) * LDT + lrow] = av.z;
        As[(lk + 3) * LDT + lrow] = av.w;
        Bs[(lk + 0) * LDT + lrow] = bv.x;
        Bs[(lk + 1) * LDT + lrow] = bv.y;
        Bs[(lk + 2) * LDT + lrow] = bv.z;
        Bs[(lk + 3) * LDT + lrow] = bv.w;
        __syncthreads();
#pragma unroll
        for (int kk = 0; kk < 16; ++kk) {
            float4 a = *(const float4*)&As[kk * LDT + ty * 4];
            float4 b = *(const float4*)&Bs[kk * LDT + tx * 4];
            float ar[4] = {a.x, a.y, a.z, a.w};
            float br[4] = {b.x, b.y, b.z, b.w};
#pragma unroll
            for (int i = 0; i < 4; ++i)
#pragma unroll
                for (int j = 0; j < 4; ++j)
                    acc[i][j] = fmaf(ar[i], br[j], acc[i][j]);
        }
        __syncthreads();
    }
#pragma unroll
    for (int i = 0; i < 4; ++i) {
        const int row = bi + ty * 4 + i;
#pragma unroll
        for (int j = 0; j < 4; ++j) {
            const int col = bj + tx * 4 + j;
            const float bb = bias ? bias[col] : 0.0f;
            C[row * C_DIM + col] = acc[i][j] + bb;
        }
    }
}

// ---------------------------------------------------------------------------
// logits[n,g,m] = 0.125 * dot(q[n, g*64 : g*64+64], k[m, g*64 : g*64+64])
// block: 64 n x 64 m for one group g. K = 64 (fully staged in LDS).
// ---------------------------------------------------------------------------
__global__ __launch_bounds__(256) void aff_kernel(const float* __restrict__ q,
                                                  const float* __restrict__ k,
                                                  float* __restrict__ logits)
{
    constexpr int LDT = 68;
    __shared__ float qs[64 * LDT];          // qs[d][n]
    __shared__ float ks[64 * LDT];          // ks[d][m]
    const int t  = threadIdx.x;
    const int g  = blockIdx.z;
    const int n0 = blockIdx.y * 64;
    const int m0 = blockIdx.x * 64;
    const int row = t >> 2;
    const int c4  = (t & 3) * 4;
#pragma unroll
    for (int u = 0; u < 4; ++u) {
        const int d = c4 + u * 16;
        float4 qv = *(const float4*)&q[(n0 + row) * C_DIM + g * 64 + d];
        float4 kv = *(const float4*)&k[(m0 + row) * C_DIM + g * 64 + d];
        qs[(d + 0) * LDT + row] = qv.x;
        qs[(d + 1) * LDT + row] = qv.y;
        qs[(d + 2) * LDT + row] = qv.z;
        qs[(d + 3) * LDT + row] = qv.w;
        ks[(d + 0) * LDT + row] = kv.x;
        ks[(d + 1) * LDT + row] = kv.y;
        ks[(d + 2) * LDT + row] = kv.z;
        ks[(d + 3) * LDT + row] = kv.w;
    }
    __syncthreads();
    const int tx = t & 15, ty = t >> 4;
    float acc[4][4] = {};
#pragma unroll 8
    for (int d = 0; d < 64; ++d) {
        float4 a = *(const float4*)&qs[d * LDT + ty * 4];
        float4 b = *(const float4*)&ks[d * LDT + tx * 4];
        float ar[4] = {a.x, a.y, a.z, a.w};
        float br[4] = {b.x, b.y, b.z, b.w};
#pragma unroll
        for (int i = 0; i < 4; ++i)
#pragma unroll
            for (int j = 0; j < 4; ++j)
                acc[i][j] = fmaf(ar[i], br[j], acc[i][j]);
    }
#pragma unroll
    for (int i = 0; i < 4; ++i) {
        const int n = n0 + ty * 4 + i;
        float4 v;
        v.x = acc[i][0] * 0.125f;
        v.y = acc[i][1] * 0.125f;
        v.z = acc[i][2] * 0.125f;
        v.w = acc[i][3] * 0.125f;
        *(float4*)&logits[n * LROW + g * N_ROIS + m0 + tx * 4] = v;
    }
}

// ---------------------------------------------------------------------------
// logits[n,g,m] += log(max(relu(emb(n,m)·Wg[g] + bg[g]), 1e-6))
// One block per (n, 256-wide m-chunk); thread = one m. emb never materialized.
// ---------------------------------------------------------------------------
__global__ __launch_bounds__(256) void pos_kernel(const float* __restrict__ rois,
                                                  const float* __restrict__ Wg,
                                                  const float* __restrict__ bg,
                                                  float* __restrict__ logits)
{
    __shared__ float wg_s[G_DIM * PE_DIM];
    __shared__ float bg_s[G_DIM];
    const int t = threadIdx.x;
    *(float4*)&wg_s[t * 4] = *(const float4*)&Wg[t * 4];
    if (t < G_DIM) bg_s[t] = bg[t];
    const int n = blockIdx.x;
    const int m = blockIdx.y * 256 + t;
    const float x1n = rois[n * 5 + 1], y1n = rois[n * 5 + 2];
    const float x2n = rois[n * 5 + 3], y2n = rois[n * 5 + 4];
    const float x1m = rois[m * 5 + 1], y1m = rois[m * 5 + 2];
    const float x2m = rois[m * 5 + 3], y2m = rois[m * 5 + 4];
    __syncthreads();
    const float cxn = (x1n + x2n) * 0.5f, cyn = (y1n + y2n) * 0.5f;
    const float wn  = x2n - x1n + 1.0f,   hn  = y2n - y1n + 1.0f;
    const float cxm = (x1m + x2m) * 0.5f, cym = (y1m + y2m) * 0.5f;
    const float wm  = x2m - x1m + 1.0f,   hm  = y2m - y1m + 1.0f;
    float pmv[4];
    pmv[0] = __logf(fmaxf(fabsf((cxn - cxm) / wn), 1e-3f));
    pmv[1] = __logf(fmaxf(fabsf((cyn - cym) / hn), 1e-3f));
    pmv[2] = __logf(wn / wm);
    pmv[3] = __logf(hn / hm);
    const float dimv[8] = {1.0f, 2.3713737057f, 5.6234132519f, 13.3352143216f,
                           31.6227766017f, 74.9894209332f, 177.8279410039f, 421.6965034286f};
    float e[64];
#pragma unroll
    for (int f = 0; f < 4; ++f) {
        const float base = 100.0f * pmv[f];
#pragma unroll
        for (int r = 0; r < 8; ++r) {
            float s, c;
            __sincosf(base / dimv[r], &s, &c);
            e[f * 16 + r]     = s;   // sin block  (first 8 of each 16)
            e[f * 16 + 8 + r] = c;   // cos block  (second 8)
        }
    }
    float* lp = logits + n * LROW + m;
#pragma unroll
    for (int g = 0; g < G_DIM; ++g) {
        float acc = bg_s[g];
#pragma unroll
        for (int p = 0; p < PE_DIM; ++p)
            acc = fmaf(e[p], wg_s[g * PE_DIM + p], acc);
        // relu then clip(min=1e-6) then log  ==  log(max(acc, 1e-6))
        lp[g * N_ROIS] += __logf(fmaxf(acc, 1e-6f));
    }
}

// ---------------------------------------------------------------------------
// In-place softmax over the last (m) axis; one block per (n,g) row of 1024.
// ---------------------------------------------------------------------------
__global__ __launch_bounds__(256) void softmax_kernel(float* __restrict__ logits)
{
    float* p = logits + (size_t)blockIdx.x * N_ROIS;
    const int t = threadIdx.x;
    float4 v = *(const float4*)&p[t * 4];
    __shared__ float red[8];
    float mx = fmaxf(fmaxf(v.x, v.y), fmaxf(v.z, v.w));
#pragma unroll
    for (int o = 1; o < 64; o <<= 1) mx = fmaxf(mx, __shfl_xor(mx, o));
    if ((t & 63) == 0) red[t >> 6] = mx;
    __syncthreads();
    mx = fmaxf(fmaxf(red[0], red[1]), fmaxf(red[2], red[3]));
    v.x = __expf(v.x - mx);
    v.y = __expf(v.y - mx);
    v.z = __expf(v.z - mx);
    v.w = __expf(v.w - mx);
    float s = v.x + v.y + v.z + v.w;
#pragma unroll
    for (int o = 1; o < 64; o <<= 1) s += __shfl_xor(s, o);
    if ((t & 63) == 0) red[4 + (t >> 6)] = s;
    __syncthreads();
    s = red[4] + red[5] + red[6] + red[7];
    const float inv = 1.0f / s;
    v.x *= inv; v.y *= inv; v.z *= inv; v.w *= inv;
    *(float4*)&p[t * 4] = v;
}

// ---------------------------------------------------------------------------
// rel[n, g*64+d] = sum_m sm[n,g,m] * FW[m, g*64+d] + bv[g*64+d]
// Grouped GEMM: per g, [64n x 1024m] @ [1024m x 64d]. BK=16.
// ---------------------------------------------------------------------------
__global__ __launch_bounds__(256) void rel_kernel(const float* __restrict__ sm,
                                                  const float* __restrict__ FW,
                                                  const float* __restrict__ bv,
                                                  float* __restrict__ out)
{
    constexpr int LDT = 68;
    __shared__ float As[16 * LDT];          // As[kk][n]
    __shared__ float Bs[16 * LDT];          // Bs[kk][d]
    const int t  = threadIdx.x;
    const int g  = blockIdx.y;
    const int n0 = blockIdx.x * 64;
    const int tx = t & 15, ty = t >> 4;
    const int lrow = t >> 2, lk = (t & 3) * 4;
    const int bkk = t >> 4, bcol = (t & 15) * 4;
    float acc[4][4] = {};
    for (int k0 = 0; k0 < N_ROIS; k0 += 16) {
        float4 av = *(const float4*)&sm[(n0 + lrow) * LROW + g * N_ROIS + k0 + lk];
        float4 bw = *(const float4*)&FW[(k0 + bkk) * C_DIM + g * 64 + bcol];
        As[(lk + 0) * LDT + lrow] = av.x;
        As[(lk + 1) * LDT + lrow] = av.y;
        As[(lk + 2) * LDT + lrow] = av.z;
        As[(lk + 3) * LDT + lrow] = av.w;
        *(float4*)&Bs[bkk * LDT + bcol] = bw;
        __syncthreads();
#pragma unroll
        for (int kk = 0; kk < 16; ++kk) {
            float4 a = *(const float4*)&As[kk * LDT + ty * 4];
            float4 b = *(const float4*)&Bs[kk * LDT + tx * 4];
            float ar[4] = {a.x, a.y, a.z, a.w};
            float br[4] = {b.x, b.y, b.z, b.w};
#pragma unroll
            for (int i = 0; i < 4; ++i)
#pragma unroll
                for (int j = 0; j < 4; ++j)
                    acc[i][j] = fmaf(ar[i], br[j], acc[i][j]);
        }
        __syncthreads();
    }
#pragma unroll
    for (int i = 0; i < 4; ++i) {
        const int nrow = n0 + ty * 4 + i;
#pragma unroll
        for (int j = 0; j < 4; ++j) {
            const int col = g * 64 + tx * 4 + j;
            out[nrow * C_DIM + col] = acc[i][j] + bv[col];
        }
    }
}

extern "C" void kernel_launch(void* const* d_in, const int* in_sizes, int n_in,
                              void* d_out, int out_size, void* d_ws, size_t ws_size,
                              hipStream_t stream)
{
    const float* feats = (const float*)d_in[0];
    const float* rois  = (const float*)d_in[1];
    const float* Wq    = (const float*)d_in[2];
    const float* bq    = (const float*)d_in[3];
    const float* Wk    = (const float*)d_in[4];
    const float* bk    = (const float*)d_in[5];
    const float* Wg    = (const float*)d_in[6];
    const float* bg    = (const float*)d_in[7];
    const float* Wv    = (const float*)d_in[8];
    const float* bv    = (const float*)d_in[9];
    float* out = (float*)d_out;
    float* ws  = (float*)d_ws;

    float* q      = ws;                    // 1M floats
    float* k      = ws + (1u << 20);       // 1M
    float* FW     = ws + (2u << 20);       // 1M  (feats @ Wv^T)
    float* logits = ws + (3u << 20);       // 16M ([N][G][M], softmax in-place)

    dim3 gg(16, 16);
    gemm_nt_bias<<<gg, 256, 0, stream>>>(feats, Wq, bq, q);
    gemm_nt_bias<<<gg, 256, 0, stream>>>(feats, Wk, bk, k);
    gemm_nt_bias<<<gg, 256, 0, stream>>>(feats, Wv, nullptr, FW);
    aff_kernel<<<dim3(16, 16, 16), 256, 0, stream>>>(q, k, logits);
    pos_kernel<<<dim3(1024, 4), 256, 0, stream>>>(rois, Wg, bg, logits);
    softmax_kernel<<<16384, 256, 0, stream>>>(logits);
    rel_kernel<<<dim3(16, 16), 256, 0, stream>>>(logits, FW, bv, out);
}

// Round 2
// 136.047 us; speedup vs baseline: 2.4768x; 2.4768x over previous
//
#include <hip/hip_runtime.h>
#include <math.h>

#define N_ROIS 1024
#define C_DIM  1024
#define LROW   16384

typedef __attribute__((ext_vector_type(8))) short short8;
typedef __attribute__((ext_vector_type(4))) float f32x4;

__device__ __forceinline__ unsigned short f2bf(float x) {
    union { float f; unsigned u; } v; v.f = x;
    unsigned r = v.u + 0x7fffu + ((v.u >> 16) & 1u);
    return (unsigned short)(r >> 16);
}

// ---------------------------------------------------------------------------
// Bulk f32 -> bf16 convert of 4 tensors (1M elems each).
// ---------------------------------------------------------------------------
__global__ __launch_bounds__(256) void cvt_kernel(
    const float* __restrict__ s0, const float* __restrict__ s1,
    const float* __restrict__ s2, const float* __restrict__ s3,
    unsigned short* __restrict__ d0, unsigned short* __restrict__ d1,
    unsigned short* __restrict__ d2, unsigned short* __restrict__ d3)
{
    const float* s; unsigned short* d;
    switch (blockIdx.y) {
        case 0:  s = s0; d = d0; break;
        case 1:  s = s1; d = d1; break;
        case 2:  s = s2; d = d2; break;
        default: s = s3; d = d3; break;
    }
    const int i = (blockIdx.x * 256 + threadIdx.x) * 8;
    float4 a = *(const float4*)&s[i];
    float4 b = *(const float4*)&s[i + 4];
    short8 o;
    o[0] = (short)f2bf(a.x); o[1] = (short)f2bf(a.y);
    o[2] = (short)f2bf(a.z); o[3] = (short)f2bf(a.w);
    o[4] = (short)f2bf(b.x); o[5] = (short)f2bf(b.y);
    o[6] = (short)f2bf(b.z); o[7] = (short)f2bf(b.w);
    *(short8*)&d[i] = o;
}

// ---------------------------------------------------------------------------
// MFMA NT-GEMM core: C(128 x BN) += A(128 x K) * B(BN x K)^T, bf16 in, f32 acc.
// 256 threads = 4 waves, each wave a 64 x (BN/2) sub-tile of 16x16 frags.
// LDS rows padded 32->40 elems (80 B): frag ds_read_b128 lands at minimum
// bank aliasing (2-way, free per m136).
// ---------------------------------------------------------------------------
template<int BN>
__device__ __forceinline__ void mfma_core(
    const unsigned short* __restrict__ A, const unsigned short* __restrict__ B,
    int lda, int ldb, int K, int m0, int n0, int t,
    f32x4 (&acc)[4][BN / 32])
{
    constexpr int NI  = BN / 32;
    constexpr int LDT = 40;
    __shared__ unsigned short As[128 * LDT];
    __shared__ unsigned short Bs[BN * LDT];

    const int row = t >> 2;          // 0..63
    const int kc  = (t & 3) * 8;     // k element offset of this thread's 16B chunk

    const unsigned short* gA0 = A + (size_t)(m0 + row) * lda + kc;
    const unsigned short* gA1 = gA0 + (size_t)64 * lda;
    unsigned short* sA0 = &As[row * LDT + kc];
    unsigned short* sA1 = sA0 + 64 * LDT;
    const unsigned short* gB0 = B + (size_t)(n0 + row) * ldb + kc;
    unsigned short* sB0 = &Bs[row * LDT + kc];
    const unsigned short* gB1 = gB0 + (size_t)64 * ldb;
    unsigned short* sB1 = sB0 + 64 * LDT;

    int4 ra0 = *(const int4*)gA0;
    int4 ra1 = *(const int4*)gA1;
    int4 rb0 = *(const int4*)gB0;
    int4 rb1 = {};
    if (BN == 128) rb1 = *(const int4*)gB1;

    const int lane = t & 63;
    const int wid  = t >> 6;
    const int wm = (wid & 1) * 64;
    const int wn = (wid >> 1) * (BN / 2);
    const unsigned short* pa = &As[(wm + (lane & 15)) * LDT + (lane >> 4) * 8];
    const unsigned short* pb = &Bs[(wn + (lane & 15)) * LDT + (lane >> 4) * 8];

    for (int k0 = 0; k0 < K; k0 += 32) {
        *(int4*)sA0 = ra0;
        *(int4*)sA1 = ra1;
        *(int4*)sB0 = rb0;
        if (BN == 128) *(int4*)sB1 = rb1;
        __syncthreads();
        if (k0 + 32 < K) {           // prefetch next K-slice while LDS is consumed
            ra0 = *(const int4*)(gA0 + k0 + 32);
            ra1 = *(const int4*)(gA1 + k0 + 32);
            rb0 = *(const int4*)(gB0 + k0 + 32);
            if (BN == 128) rb1 = *(const int4*)(gB1 + k0 + 32);
        }
        short8 af[4], bfr[NI];
#pragma unroll
        for (int mi = 0; mi < 4; ++mi) af[mi] = *(const short8*)(pa + mi * 16 * LDT);
#pragma unroll
        for (int ni = 0; ni < NI; ++ni) bfr[ni] = *(const short8*)(pb + ni * 16 * LDT);
#pragma unroll
        for (int mi = 0; mi < 4; ++mi)
#pragma unroll
            for (int ni = 0; ni < NI; ++ni)
                acc[mi][ni] = __builtin_amdgcn_mfma_f32_16x16x32_bf16(
                    af[mi], bfr[ni], acc[mi][ni], 0, 0, 0);
        __syncthreads();
    }
}

// ---------------------------------------------------------------------------
// Three 1024^3 NT GEMMs in one launch (z selects triple): q, k, FWt. bf16 out.
// ---------------------------------------------------------------------------
struct Triples {
    const unsigned short* A[3];
    const unsigned short* B[3];
    unsigned short*       C[3];
    const float*          bias[3];
};

__global__ __launch_bounds__(256) void gemm3_kernel(Triples tr)
{
    const int z  = blockIdx.z;
    const int m0 = blockIdx.y * 128, n0 = blockIdx.x * 128;
    const int t  = threadIdx.x;
    f32x4 acc[4][4];
    const f32x4 z4 = {0.f, 0.f, 0.f, 0.f};
#pragma unroll
    for (int i = 0; i < 4; ++i)
#pragma unroll
        for (int j = 0; j < 4; ++j) acc[i][j] = z4;

    mfma_core<128>(tr.A[z], tr.B[z], 1024, 1024, 1024, m0, n0, t, acc);

    const float* bias = tr.bias[z];
    unsigned short* C = tr.C[z];
    const int lane = t & 63, wid = t >> 6;
    const int wm = (wid & 1) * 64, wn = (wid >> 1) * 64;
    const int r0 = (lane >> 4) * 4, cc = lane & 15;
#pragma unroll
    for (int mi = 0; mi < 4; ++mi)
#pragma unroll
        for (int ni = 0; ni < 4; ++ni) {
            const int col = n0 + wn + ni * 16 + cc;
            const float bb = bias ? bias[col] : 0.f;
#pragma unroll
            for (int r = 0; r < 4; ++r) {
                const int rowi = m0 + wm + mi * 16 + r0 + r;
                C[(size_t)rowi * 1024 + col] = f2bf(acc[mi][ni][r] + bb);
            }
        }
}

// ---------------------------------------------------------------------------
// Grouped NT GEMM (z = group), f32 out: used for aff (BN=128, K=64, x0.125)
// and rel (BN=64, K=1024, +bias).
// ---------------------------------------------------------------------------
template<int BN, bool HAS_BIAS>
__global__ __launch_bounds__(256) void gemmz_kernel(
    const unsigned short* __restrict__ A, const unsigned short* __restrict__ B,
    float* __restrict__ C, const float* __restrict__ bias,
    int lda, int ldb, int ldc, int K, float scale,
    long zA, long zB, long zC, int zBias)
{
    constexpr int NI = BN / 32;
    const int z  = blockIdx.z;
    const int m0 = blockIdx.y * 128, n0 = blockIdx.x * BN;
    const int t  = threadIdx.x;
    f32x4 acc[4][NI];
    const f32x4 z4 = {0.f, 0.f, 0.f, 0.f};
#pragma unroll
    for (int i = 0; i < 4; ++i)
#pragma unroll
        for (int j = 0; j < NI; ++j) acc[i][j] = z4;

    mfma_core<BN>(A + (size_t)z * zA, B + (size_t)z * zB, lda, ldb, K, m0, n0, t, acc);

    float* Cz = C + (size_t)z * zC;
    const float* bz = bias ? bias + (size_t)z * zBias : nullptr;
    const int lane = t & 63, wid = t >> 6;
    const int wm = (wid & 1) * 64, wn = (wid >> 1) * (BN / 2);
    const int r0 = (lane >> 4) * 4, cc = lane & 15;
#pragma unroll
    for (int mi = 0; mi < 4; ++mi)
#pragma unroll
        for (int ni = 0; ni < NI; ++ni) {
            const int col = n0 + wn + ni * 16 + cc;
            const float bb = HAS_BIAS ? bz[col] : 0.f;
#pragma unroll
            for (int r = 0; r < 4; ++r) {
                const int rowi = m0 + wm + mi * 16 + r0 + r;
                Cz[(size_t)rowi * ldc + col] = acc[mi][ni][r] * scale + bb;
            }
        }
}

// ---------------------------------------------------------------------------
// logits[n,g,m] += log(max(relu(emb(n,m)·Wg[g] + bg[g]), 1e-6))
// 2 pairs per thread share float4 Wg reads; no e[] array (register-resident).
// ---------------------------------------------------------------------------
__global__ __launch_bounds__(256) void pos_kernel(
    const float* __restrict__ rois, const float* __restrict__ Wg,
    const float* __restrict__ bg, float* __restrict__ logits)
{
    __shared__ float wg_s[1024];
    __shared__ float bg_s[16];
    const int t = threadIdx.x;
    *(float4*)&wg_s[t * 4] = *(const float4*)&Wg[t * 4];
    if (t < 16) bg_s[t] = bg[t];
    const int n  = blockIdx.x;
    const int ma = blockIdx.y * 512 + t;
    const int mb = ma + 256;
    const float x1n = rois[n*5+1],  y1n = rois[n*5+2],  x2n = rois[n*5+3],  y2n = rois[n*5+4];
    const float x1a = rois[ma*5+1], y1a = rois[ma*5+2], x2a = rois[ma*5+3], y2a = rois[ma*5+4];
    const float x1b = rois[mb*5+1], y1b = rois[mb*5+2], x2b = rois[mb*5+3], y2b = rois[mb*5+4];
    __syncthreads();
    const float cxn = (x1n + x2n) * 0.5f, cyn = (y1n + y2n) * 0.5f;
    const float wn  = x2n - x1n + 1.f,    hn  = y2n - y1n + 1.f;
    const float iwn = 1.f / wn, ihn = 1.f / hn;
    float pa4[4], pb4[4];
    {
        const float cxa = (x1a + x2a) * 0.5f, cya = (y1a + y2a) * 0.5f;
        const float wa  = x2a - x1a + 1.f,    ha  = y2a - y1a + 1.f;
        pa4[0] = __logf(fmaxf(fabsf((cxn - cxa) * iwn), 1e-3f));
        pa4[1] = __logf(fmaxf(fabsf((cyn - cya) * ihn), 1e-3f));
        pa4[2] = __logf(wn / wa);
        pa4[3] = __logf(hn / ha);
        const float cxb = (x1b + x2b) * 0.5f, cyb = (y1b + y2b) * 0.5f;
        const float wb  = x2b - x1b + 1.f,    hb  = y2b - y1b + 1.f;
        pb4[0] = __logf(fmaxf(fabsf((cxn - cxb) * iwn), 1e-3f));
        pb4[1] = __logf(fmaxf(fabsf((cyn - cyb) * ihn), 1e-3f));
        pb4[2] = __logf(wn / wb);
        pb4[3] = __logf(hn / hb);
    }
    float acca[16], accb[16];
#pragma unroll
    for (int g = 0; g < 16; ++g) { acca[g] = bg_s[g]; accb[g] = bg_s[g]; }
    const float invd[8] = {1.f, 0.42169650342f, 0.1778279410f, 0.07498942093f,
                           0.0316227766f, 0.01333521432f, 0.005623413252f, 0.002371373706f};
#pragma unroll
    for (int f = 0; f < 4; ++f) {
        const float ba  = 100.f * pa4[f];
        const float bb2 = 100.f * pb4[f];
#pragma unroll
        for (int r4 = 0; r4 < 2; ++r4) {
            float sa[4], ca[4], sb[4], cb[4];
#pragma unroll
            for (int u = 0; u < 4; ++u) {
                const float iv = invd[r4 * 4 + u];
                __sincosf(ba  * iv, &sa[u], &ca[u]);
                __sincosf(bb2 * iv, &sb[u], &cb[u]);
            }
#pragma unroll
            for (int g = 0; g < 16; ++g) {
                const float4 wsv = *(const float4*)&wg_s[g * 64 + f * 16 + r4 * 4];
                const float4 wcv = *(const float4*)&wg_s[g * 64 + f * 16 + 8 + r4 * 4];
                acca[g] += sa[0]*wsv.x + sa[1]*wsv.y + sa[2]*wsv.z + sa[3]*wsv.w
                         + ca[0]*wcv.x + ca[1]*wcv.y + ca[2]*wcv.z + ca[3]*wcv.w;
                accb[g] += sb[0]*wsv.x + sb[1]*wsv.y + sb[2]*wsv.z + sb[3]*wsv.w
                         + cb[0]*wcv.x + cb[1]*wcv.y + cb[2]*wcv.z + cb[3]*wcv.w;
            }
        }
    }
    float* lp = logits + (size_t)n * LROW;
#pragma unroll
    for (int g = 0; g < 16; ++g) {
        lp[g * N_ROIS + ma] += __logf(fmaxf(acca[g], 1e-6f));
        lp[g * N_ROIS + mb] += __logf(fmaxf(accb[g], 1e-6f));
    }
}

// ---------------------------------------------------------------------------
// Row softmax over m (1024); reads f32 row, writes bf16 probs in place
// (bf16 row occupies the first half of the f32 row's bytes).
// ---------------------------------------------------------------------------
__global__ __launch_bounds__(256) void softmax_kernel(float* __restrict__ logits)
{
    float* p = logits + (size_t)blockIdx.x * N_ROIS;
    unsigned short* ob = (unsigned short*)p;
    const int t = threadIdx.x;
    float4 v = *(const float4*)&p[t * 4];
    __shared__ float red[8];
    float mx = fmaxf(fmaxf(v.x, v.y), fmaxf(v.z, v.w));
#pragma unroll
    for (int o = 1; o < 64; o <<= 1) mx = fmaxf(mx, __shfl_xor(mx, o));
    if ((t & 63) == 0) red[t >> 6] = mx;
    __syncthreads();
    mx = fmaxf(fmaxf(red[0], red[1]), fmaxf(red[2], red[3]));
    v.x = __expf(v.x - mx); v.y = __expf(v.y - mx);
    v.z = __expf(v.z - mx); v.w = __expf(v.w - mx);
    float s = v.x + v.y + v.z + v.w;
#pragma unroll
    for (int o = 1; o < 64; o <<= 1) s += __shfl_xor(s, o);
    if ((t & 63) == 0) red[4 + (t >> 6)] = s;
    __syncthreads();
    s = red[4] + red[5] + red[6] + red[7];
    const float inv = 1.0f / s;
    const unsigned lo = (unsigned)f2bf(v.x * inv) | ((unsigned)f2bf(v.y * inv) << 16);
    const unsigned hi = (unsigned)f2bf(v.z * inv) | ((unsigned)f2bf(v.w * inv) << 16);
    // every thread's f32 read happened before the barriers above -> safe overwrite
    *(uint2*)&ob[t * 4] = make_uint2(lo, hi);
}

extern "C" void kernel_launch(void* const* d_in, const int* in_sizes, int n_in,
                              void* d_out, int out_size, void* d_ws, size_t ws_size,
                              hipStream_t stream)
{
    const float* feats = (const float*)d_in[0];
    const float* rois  = (const float*)d_in[1];
    const float* Wq    = (const float*)d_in[2];
    const float* bq    = (const float*)d_in[3];
    const float* Wk    = (const float*)d_in[4];
    const float* bk    = (const float*)d_in[5];
    const float* Wg    = (const float*)d_in[6];
    const float* bg    = (const float*)d_in[7];
    const float* Wv    = (const float*)d_in[8];
    const float* bv    = (const float*)d_in[9];
    float* out = (float*)d_out;

    char* wsb = (char*)d_ws;
    // logits f32 [N][G][M] occupies [0, 64MB); bf16 weight copies live there
    // only BEFORE aff overwrites it (stream-ordered, so safe).
    float*          logits = (float*)wsb;
    unsigned short* smb    = (unsigned short*)wsb;              // bf16 probs, in-place
    unsigned short* Wqb    = (unsigned short*)(wsb + (0ull  << 20));
    unsigned short* Wkb    = (unsigned short*)(wsb + (2ull  << 20));
    unsigned short* Wvb    = (unsigned short*)(wsb + (4ull  << 20));
    unsigned short* featsb = (unsigned short*)(wsb + (64ull << 20));
    unsigned short* qb     = (unsigned short*)(wsb + (66ull << 20));
    unsigned short* kb     = (unsigned short*)(wsb + (68ull << 20));
    unsigned short* FWtb   = (unsigned short*)(wsb + (70ull << 20));

    cvt_kernel<<<dim3(512, 4), 256, 0, stream>>>(feats, Wq, Wk, Wv,
                                                 featsb, Wqb, Wkb, Wvb);

    Triples tr;
    tr.A[0] = featsb; tr.B[0] = Wqb;    tr.C[0] = qb;   tr.bias[0] = bq;
    tr.A[1] = featsb; tr.B[1] = Wkb;    tr.C[1] = kb;   tr.bias[1] = bk;
    tr.A[2] = Wvb;    tr.B[2] = featsb; tr.C[2] = FWtb; tr.bias[2] = nullptr; // FWt[c][m]
    gemm3_kernel<<<dim3(8, 8, 3), 256, 0, stream>>>(tr);

    // aff: logits[n, g, m] = 0.125 * q_g[n,:] . k_g[m,:]
    gemmz_kernel<128, false><<<dim3(8, 8, 16), 256, 0, stream>>>(
        qb, kb, logits, nullptr,
        1024, 1024, LROW, 64, 0.125f,
        64L, 64L, 1024L, 0);

    pos_kernel<<<dim3(1024, 2), 256, 0, stream>>>(rois, Wg, bg, logits);

    softmax_kernel<<<16384, 256, 0, stream>>>(logits);

    // rel: out[n, g*64+d] = sum_m sm[n,g,m] * FWt[g*64+d, m] + bv[g*64+d]
    // smb row (n,g) lives at ushort offset n*32768 + g*2048 (bf16 in f32 row).
    gemmz_kernel<64, true><<<dim3(1, 8, 16), 256, 0, stream>>>(
        smb, FWtb, out, bv,
        32768, 1024, 1024, 1024, 1.0f,
        2048L, 65536L, 64L, 64);
}

// Round 3
// 115.032 us; speedup vs baseline: 2.9293x; 1.1827x over previous
//
#include <hip/hip_runtime.h>
#include <math.h>

#define N_ROIS 1024
#define C_DIM  1024

typedef __attribute__((ext_vector_type(8))) short short8;
typedef __attribute__((ext_vector_type(4))) float f32x4;

__device__ __forceinline__ unsigned short f2bf(float x) {
    union { float f; unsigned u; } v; v.f = x;
    unsigned r = v.u + 0x7fffu + ((v.u >> 16) & 1u);
    return (unsigned short)(r >> 16);
}
__device__ __forceinline__ float bf2f(unsigned short u) {
    return __uint_as_float((unsigned)u << 16);
}

// ---------------------------------------------------------------------------
// Bulk f32 -> bf16 convert of 4 tensors (1M elems each).
// ---------------------------------------------------------------------------
__global__ __launch_bounds__(256) void cvt_kernel(
    const float* __restrict__ s0, const float* __restrict__ s1,
    const float* __restrict__ s2, const float* __restrict__ s3,
    unsigned short* __restrict__ d0, unsigned short* __restrict__ d1,
    unsigned short* __restrict__ d2, unsigned short* __restrict__ d3)
{
    const float* s; unsigned short* d;
    switch (blockIdx.y) {
        case 0:  s = s0; d = d0; break;
        case 1:  s = s1; d = d1; break;
        case 2:  s = s2; d = d2; break;
        default: s = s3; d = d3; break;
    }
    const int i = (blockIdx.x * 256 + threadIdx.x) * 8;
    float4 a = *(const float4*)&s[i];
    float4 b = *(const float4*)&s[i + 4];
    short8 o;
    o[0] = (short)f2bf(a.x); o[1] = (short)f2bf(a.y);
    o[2] = (short)f2bf(a.z); o[3] = (short)f2bf(a.w);
    o[4] = (short)f2bf(b.x); o[5] = (short)f2bf(b.y);
    o[6] = (short)f2bf(b.z); o[7] = (short)f2bf(b.w);
    *(short8*)&d[i] = o;
}

// ---------------------------------------------------------------------------
// MFMA NT-GEMM core (unchanged from r2): C(128 x 128) += A(128 x K)*B(128 x K)^T
// ---------------------------------------------------------------------------
__device__ __forceinline__ void mfma_core128(
    const unsigned short* __restrict__ A, const unsigned short* __restrict__ B,
    int K, int m0, int n0, int t, f32x4 (&acc)[4][4])
{
    constexpr int LDT = 40;
    __shared__ unsigned short As[128 * LDT];
    __shared__ unsigned short Bs[128 * LDT];
    const int row = t >> 2;
    const int kc  = (t & 3) * 8;
    const unsigned short* gA0 = A + (size_t)(m0 + row) * 1024 + kc;
    const unsigned short* gA1 = gA0 + (size_t)64 * 1024;
    unsigned short* sA0 = &As[row * LDT + kc];
    unsigned short* sA1 = sA0 + 64 * LDT;
    const unsigned short* gB0 = B + (size_t)(n0 + row) * 1024 + kc;
    const unsigned short* gB1 = gB0 + (size_t)64 * 1024;
    unsigned short* sB0 = &Bs[row * LDT + kc];
    unsigned short* sB1 = sB0 + 64 * LDT;
    int4 ra0 = *(const int4*)gA0;
    int4 ra1 = *(const int4*)gA1;
    int4 rb0 = *(const int4*)gB0;
    int4 rb1 = *(const int4*)gB1;
    const int lane = t & 63, wid = t >> 6;
    const int wm = (wid & 1) * 64, wn = (wid >> 1) * 64;
    const unsigned short* pa = &As[(wm + (lane & 15)) * LDT + (lane >> 4) * 8];
    const unsigned short* pb = &Bs[(wn + (lane & 15)) * LDT + (lane >> 4) * 8];
    for (int k0 = 0; k0 < K; k0 += 32) {
        *(int4*)sA0 = ra0; *(int4*)sA1 = ra1;
        *(int4*)sB0 = rb0; *(int4*)sB1 = rb1;
        __syncthreads();
        if (k0 + 32 < K) {
            ra0 = *(const int4*)(gA0 + k0 + 32);
            ra1 = *(const int4*)(gA1 + k0 + 32);
            rb0 = *(const int4*)(gB0 + k0 + 32);
            rb1 = *(const int4*)(gB1 + k0 + 32);
        }
        short8 af[4], bfr[4];
#pragma unroll
        for (int mi = 0; mi < 4; ++mi) af[mi]  = *(const short8*)(pa + mi * 16 * LDT);
#pragma unroll
        for (int ni = 0; ni < 4; ++ni) bfr[ni] = *(const short8*)(pb + ni * 16 * LDT);
#pragma unroll
        for (int mi = 0; mi < 4; ++mi)
#pragma unroll
            for (int ni = 0; ni < 4; ++ni)
                acc[mi][ni] = __builtin_amdgcn_mfma_f32_16x16x32_bf16(
                    af[mi], bfr[ni], acc[mi][ni], 0, 0, 0);
        __syncthreads();
    }
}

struct Triples {
    const unsigned short* A[3];
    const unsigned short* B[3];
    unsigned short*       C[3];
    const float*          bias[3];
};

__global__ __launch_bounds__(256) void gemm3_kernel(Triples tr)
{
    const int z  = blockIdx.z;
    const int m0 = blockIdx.y * 128, n0 = blockIdx.x * 128;
    const int t  = threadIdx.x;
    f32x4 acc[4][4];
    const f32x4 z4 = {0.f, 0.f, 0.f, 0.f};
#pragma unroll
    for (int i = 0; i < 4; ++i)
#pragma unroll
        for (int j = 0; j < 4; ++j) acc[i][j] = z4;
    mfma_core128(tr.A[z], tr.B[z], 1024, m0, n0, t, acc);
    const float* bias = tr.bias[z];
    unsigned short* C = tr.C[z];
    const int lane = t & 63, wid = t >> 6;
    const int wm = (wid & 1) * 64, wn = (wid >> 1) * 64;
    const int r0 = (lane >> 4) * 4, cc = lane & 15;
#pragma unroll
    for (int mi = 0; mi < 4; ++mi)
#pragma unroll
        for (int ni = 0; ni < 4; ++ni) {
            const int col = n0 + wn + ni * 16 + cc;
            const float bb = bias ? bias[col] : 0.f;
#pragma unroll
            for (int r = 0; r < 4; ++r) {
                const int rowi = m0 + wm + mi * 16 + r0 + r;
                C[(size_t)rowi * 1024 + col] = f2bf(acc[mi][ni][r] + bb);
            }
        }
}

// ---------------------------------------------------------------------------
// pos via MFMA: logw[n][g][m] = bf16( log(max(relu(emb(n,m)·Wg[g]+bg[g]),1e-6)) )
// Per block: one n. A = emb tile [16 m x 64 pe] built in registers (sin/cos),
// B = Wg [16 g x 64 pe]. Wave w handles m-chunks w*16..w*16+15.
// ---------------------------------------------------------------------------
__global__ __launch_bounds__(256) void pos_mfma_kernel(
    const float* __restrict__ rois, const float* __restrict__ Wg,
    const float* __restrict__ bg, unsigned short* __restrict__ logw)
{
    __shared__ unsigned short wg_s[16 * 72];   // padded rows of 64
    __shared__ float bg_s[16];
    __shared__ float mbox[1024][4];            // cx, cy, w, h
    const int t = threadIdx.x;
    if (t < 128) {
        const int gi = t >> 3, c = (t & 7) * 8;
        unsigned short* d = &wg_s[gi * 72 + c];
#pragma unroll
        for (int u = 0; u < 8; ++u) d[u] = f2bf(Wg[gi * 64 + c + u]);
    }
    if (t < 16) bg_s[t] = bg[t];
#pragma unroll
    for (int i = 0; i < 4; ++i) {
        const int m = t + i * 256;
        const float x1 = rois[m * 5 + 1], y1 = rois[m * 5 + 2];
        const float x2 = rois[m * 5 + 3], y2 = rois[m * 5 + 4];
        mbox[m][0] = (x1 + x2) * 0.5f;
        mbox[m][1] = (y1 + y2) * 0.5f;
        mbox[m][2] = x2 - x1 + 1.f;
        mbox[m][3] = y2 - y1 + 1.f;
    }
    const int n = blockIdx.x;
    const float x1 = rois[n * 5 + 1], y1 = rois[n * 5 + 2];
    const float x2 = rois[n * 5 + 3], y2 = rois[n * 5 + 4];
    const float cxn = (x1 + x2) * 0.5f, cyn = (y1 + y2) * 0.5f;
    const float wn = x2 - x1 + 1.f, hn = y2 - y1 + 1.f;
    const float iwn = 1.f / wn, ihn = 1.f / hn;
    const float lwn = __logf(wn), lhn = __logf(hn);
    __syncthreads();

    const int lane = t & 63, w = t >> 6;
    const int g  = lane & 15;
    const int qw = lane >> 4;               // 0..3
    const float coff = (qw & 1) ? 1.5707963268f : 0.f;   // cos = sin(x + pi/2)
    const int f0 = qw >> 1;                 // 0|1 for ks=0; f0+2 for ks=1
    const short8 bf0 = *(const short8*)&wg_s[g * 72 + qw * 8];
    const short8 bf1 = *(const short8*)&wg_s[g * 72 + qw * 8 + 32];
    const float bgv = bg_s[g];
    const float invd[8] = {1.f, 0.42169650342f, 0.1778279410f, 0.07498942093f,
                           0.0316227766f, 0.01333521432f, 0.005623413252f, 0.002371373706f};
    unsigned short* outp = logw + (size_t)n * 16384;

    for (int c = w * 16; c < w * 16 + 16; ++c) {
        const int ma = c * 16 + (lane & 15);          // A row
        float4 mb = *(const float4*)&mbox[ma][0];     // cx, cy, w, h
        // pm for f0 (0=dX,1=dY) and f0+2 (2=dW,3=dH)
        float p0 = (f0 == 0)
                 ? __logf(fmaxf(fabsf((cxn - mb.x) * iwn), 1e-3f))
                 : __logf(fmaxf(fabsf((cyn - mb.y) * ihn), 1e-3f));
        float p1 = (f0 == 0) ? (lwn - __logf(mb.z)) : (lhn - __logf(mb.w));
        p0 *= 100.f; p1 *= 100.f;
        short8 af0, af1;
#pragma unroll
        for (int rr = 0; rr < 8; ++rr) {
            af0[rr] = (short)f2bf(__sinf(p0 * invd[rr] + coff));
            af1[rr] = (short)f2bf(__sinf(p1 * invd[rr] + coff));
        }
        f32x4 acc = {0.f, 0.f, 0.f, 0.f};
        acc = __builtin_amdgcn_mfma_f32_16x16x32_bf16(af0, bf0, acc, 0, 0, 0);
        acc = __builtin_amdgcn_mfma_f32_16x16x32_bf16(af1, bf1, acc, 0, 0, 0);
        // C: col = g (lane&15), rows m' = qw*4 + r  -> 4 consecutive m
        unsigned short o[4];
#pragma unroll
        for (int r = 0; r < 4; ++r)
            o[r] = f2bf(__logf(fmaxf(acc[r] + bgv, 1e-6f)));
        const unsigned lo = (unsigned)o[0] | ((unsigned)o[1] << 16);
        const unsigned hi = (unsigned)o[2] | ((unsigned)o[3] << 16);
        *(uint2*)&outp[(size_t)g * 1024 + c * 16 + qw * 4] = make_uint2(lo, hi);
    }
}

// ---------------------------------------------------------------------------
// Fused aff + logw + softmax + rel. Block = (g, 16-row n-tile), 4 waves.
//  Ph1: S = q_g . k_g^T  (MFMA, K=64; wave w covers m in [w*256,(w+1)*256))
//  Ph2: v = S*0.125 + logw; rowmax; P = exp(v - max) bf16; rowsum
//  Ph3: O = P . FWt_g^T (K=1024 split over waves), reduce, *1/sum + bv -> out
// ---------------------------------------------------------------------------
#define SROW 1028
#define PROW 1032
#define OROW 68

__global__ __launch_bounds__(256) void attn_kernel(
    const unsigned short* __restrict__ qb, const unsigned short* __restrict__ kb,
    const unsigned short* __restrict__ logw, const unsigned short* __restrict__ FWt,
    const float* __restrict__ bv, float* __restrict__ out)
{
    __shared__ float S[16 * SROW];            // 65.8 KB (Ored reuses this)
    __shared__ unsigned short P[16 * PROW];   // 33 KB
    __shared__ unsigned short qs[16 * 72];    // 2.3 KB
    __shared__ float red[256];
    __shared__ float rowmax[16], rowsum[16];
    const int t  = threadIdx.x;
    const int g  = blockIdx.x;
    const int n0 = blockIdx.y * 16;

    if (t < 128) {
        const int row = t >> 3, c = (t & 7) * 8;
        *(int4*)&qs[row * 72 + c] =
            *(const int4*)&qb[(size_t)(n0 + row) * 1024 + g * 64 + c];
    }
    __syncthreads();

    const int lane = t & 63, w = t >> 6;
    const int qw = lane >> 4, lx = lane & 15;

    // ---- Phase 1: S = q . k^T ----
    {
        const short8 aq0 = *(const short8*)&qs[lx * 72 + qw * 8];
        const short8 aq1 = *(const short8*)&qs[lx * 72 + qw * 8 + 32];
#pragma unroll 4
        for (int c = w * 16; c < w * 16 + 16; ++c) {
            const unsigned short* kp =
                &kb[(size_t)(c * 16 + lx) * 1024 + g * 64 + qw * 8];
            short8 bk0 = *(const short8*)kp;
            short8 bk1 = *(const short8*)(kp + 32);
            f32x4 acc = {0.f, 0.f, 0.f, 0.f};
            acc = __builtin_amdgcn_mfma_f32_16x16x32_bf16(aq0, bk0, acc, 0, 0, 0);
            acc = __builtin_amdgcn_mfma_f32_16x16x32_bf16(aq1, bk1, acc, 0, 0, 0);
#pragma unroll
            for (int r = 0; r < 4; ++r)
                S[(qw * 4 + r) * SROW + c * 16 + lx] = acc[r];
        }
    }
    __syncthreads();

    // ---- Phase 2: scale + logw, softmax ----
    const int rr = t >> 4;
    const int c0 = (t & 15) * 64;
    float* srow = &S[rr * SROW + c0];
    {
        const unsigned short* lwp =
            &logw[(size_t)(n0 + rr) * 16384 + (size_t)g * 1024 + c0];
        float lmax = -1e30f;
#pragma unroll
        for (int j = 0; j < 8; ++j) {
            short8 lw = *(const short8*)&lwp[j * 8];
            float4 s0 = *(const float4*)&srow[j * 8];
            float4 s1 = *(const float4*)&srow[j * 8 + 4];
            s0.x = s0.x * 0.125f + bf2f((unsigned short)lw[0]);
            s0.y = s0.y * 0.125f + bf2f((unsigned short)lw[1]);
            s0.z = s0.z * 0.125f + bf2f((unsigned short)lw[2]);
            s0.w = s0.w * 0.125f + bf2f((unsigned short)lw[3]);
            s1.x = s1.x * 0.125f + bf2f((unsigned short)lw[4]);
            s1.y = s1.y * 0.125f + bf2f((unsigned short)lw[5]);
            s1.z = s1.z * 0.125f + bf2f((unsigned short)lw[6]);
            s1.w = s1.w * 0.125f + bf2f((unsigned short)lw[7]);
            *(float4*)&srow[j * 8]     = s0;
            *(float4*)&srow[j * 8 + 4] = s1;
            lmax = fmaxf(lmax, fmaxf(fmaxf(s0.x, s0.y), fmaxf(s0.z, s0.w)));
            lmax = fmaxf(lmax, fmaxf(fmaxf(s1.x, s1.y), fmaxf(s1.z, s1.w)));
        }
        red[rr * 16 + (t & 15)] = lmax;
    }
    __syncthreads();
    if (t < 16) {
        float m = red[t * 16];
#pragma unroll
        for (int i = 1; i < 16; ++i) m = fmaxf(m, red[t * 16 + i]);
        rowmax[t] = m;
    }
    __syncthreads();
    {
        const float m = rowmax[rr];
        float sum = 0.f;
#pragma unroll
        for (int j = 0; j < 8; ++j) {
            float4 s0 = *(const float4*)&srow[j * 8];
            float4 s1 = *(const float4*)&srow[j * 8 + 4];
            float e0 = __expf(s0.x - m), e1 = __expf(s0.y - m);
            float e2 = __expf(s0.z - m), e3 = __expf(s0.w - m);
            float e4 = __expf(s1.x - m), e5 = __expf(s1.y - m);
            float e6 = __expf(s1.z - m), e7 = __expf(s1.w - m);
            sum += (e0 + e1 + e2 + e3) + (e4 + e5 + e6 + e7);
            short8 p;
            p[0] = (short)f2bf(e0); p[1] = (short)f2bf(e1);
            p[2] = (short)f2bf(e2); p[3] = (short)f2bf(e3);
            p[4] = (short)f2bf(e4); p[5] = (short)f2bf(e5);
            p[6] = (short)f2bf(e6); p[7] = (short)f2bf(e7);
            *(short8*)&P[rr * PROW + c0 + j * 8] = p;
        }
        red[rr * 16 + (t & 15)] = sum;
    }
    __syncthreads();
    if (t < 16) {
        float s = 0.f;
#pragma unroll
        for (int i = 0; i < 16; ++i) s += red[t * 16 + i];
        rowsum[t] = s;
    }
    __syncthreads();

    // ---- Phase 3: O = P . FWt^T, K split over waves ----
    float* Ored = S;                       // reuse S region: [4][16][OROW]
    {
        f32x4 acc[4];
        const f32x4 z4 = {0.f, 0.f, 0.f, 0.f};
#pragma unroll
        for (int nb = 0; nb < 4; ++nb) acc[nb] = z4;
#pragma unroll
        for (int ti = 0; ti < 2; ++ti) {
            const int kt = w + ti * 4;     // m-tile of 128
#pragma unroll
            for (int ks = 0; ks < 4; ++ks) {
                const int kc = kt * 128 + ks * 32 + qw * 8;
                short8 ap = *(const short8*)&P[lx * PROW + kc];
#pragma unroll
                for (int nb = 0; nb < 4; ++nb) {
                    const unsigned short* fp =
                        &FWt[(size_t)(g * 64 + nb * 16 + lx) * 1024 + kc];
                    short8 bf = *(const short8*)fp;
                    acc[nb] = __builtin_amdgcn_mfma_f32_16x16x32_bf16(ap, bf, acc[nb], 0, 0, 0);
                }
            }
        }
#pragma unroll
        for (int nb = 0; nb < 4; ++nb)
#pragma unroll
            for (int r = 0; r < 4; ++r)
                Ored[(w * 16 + qw * 4 + r) * OROW + nb * 16 + lx] = acc[nb][r];
    }
    __syncthreads();
    {
        const int nn = t >> 4, d0 = (t & 15) * 4;
        float4 o = *(const float4*)&Ored[nn * OROW + d0];
        float4 a1 = *(const float4*)&Ored[(16 + nn) * OROW + d0];
        float4 a2 = *(const float4*)&Ored[(32 + nn) * OROW + d0];
        float4 a3 = *(const float4*)&Ored[(48 + nn) * OROW + d0];
        o.x += a1.x + a2.x + a3.x;
        o.y += a1.y + a2.y + a3.y;
        o.z += a1.z + a2.z + a3.z;
        o.w += a1.w + a2.w + a3.w;
        const float inv = 1.f / rowsum[nn];
        float4 b4 = *(const float4*)&bv[g * 64 + d0];
        o.x = o.x * inv + b4.x;
        o.y = o.y * inv + b4.y;
        o.z = o.z * inv + b4.z;
        o.w = o.w * inv + b4.w;
        *(float4*)&out[(size_t)(n0 + nn) * 1024 + g * 64 + d0] = o;
    }
}

extern "C" void kernel_launch(void* const* d_in, const int* in_sizes, int n_in,
                              void* d_out, int out_size, void* d_ws, size_t ws_size,
                              hipStream_t stream)
{
    const float* feats = (const float*)d_in[0];
    const float* rois  = (const float*)d_in[1];
    const float* Wq    = (const float*)d_in[2];
    const float* bq    = (const float*)d_in[3];
    const float* Wk    = (const float*)d_in[4];
    const float* bk    = (const float*)d_in[5];
    const float* Wg    = (const float*)d_in[6];
    const float* bg    = (const float*)d_in[7];
    const float* Wv    = (const float*)d_in[8];
    const float* bv    = (const float*)d_in[9];
    float* out = (float*)d_out;

    char* wsb = (char*)d_ws;
    // [0,32MB): bf16 weight copies live here only until gemm3 consumes them;
    // then pos_mfma overwrites the region with logw bf16 [N][G][M] (32MB).
    unsigned short* logwb  = (unsigned short*)wsb;
    unsigned short* Wqb    = (unsigned short*)(wsb + (0ull  << 20));
    unsigned short* Wkb    = (unsigned short*)(wsb + (2ull  << 20));
    unsigned short* Wvb    = (unsigned short*)(wsb + (4ull  << 20));
    unsigned short* featsb = (unsigned short*)(wsb + (64ull << 20));
    unsigned short* qb     = (unsigned short*)(wsb + (66ull << 20));
    unsigned short* kb     = (unsigned short*)(wsb + (68ull << 20));
    unsigned short* FWtb   = (unsigned short*)(wsb + (70ull << 20));

    cvt_kernel<<<dim3(512, 4), 256, 0, stream>>>(feats, Wq, Wk, Wv,
                                                 featsb, Wqb, Wkb, Wvb);

    Triples tr;
    tr.A[0] = featsb; tr.B[0] = Wqb;    tr.C[0] = qb;   tr.bias[0] = bq;
    tr.A[1] = featsb; tr.B[1] = Wkb;    tr.C[1] = kb;   tr.bias[1] = bk;
    tr.A[2] = Wvb;    tr.B[2] = featsb; tr.C[2] = FWtb; tr.bias[2] = nullptr;
    gemm3_kernel<<<dim3(8, 8, 3), 256, 0, stream>>>(tr);

    pos_mfma_kernel<<<1024, 256, 0, stream>>>(rois, Wg, bg, logwb);

    attn_kernel<<<dim3(16, 64), 256, 0, stream>>>(qb, kb, logwb, FWtb, bv, out);
}

// Round 4
// 101.596 us; speedup vs baseline: 3.3167x; 1.1322x over previous
//
#include <hip/hip_runtime.h>
#include <math.h>

#define N_ROIS 1024
#define C_DIM  1024

typedef __attribute__((ext_vector_type(8))) short short8;
typedef __attribute__((ext_vector_type(4))) float f32x4;

__device__ __forceinline__ unsigned short f2bf(float x) {
    union { float f; unsigned u; } v; v.f = x;
    unsigned r = v.u + 0x7fffu + ((v.u >> 16) & 1u);
    return (unsigned short)(r >> 16);
}
__device__ __forceinline__ float bf2f(unsigned short u) {
    return __uint_as_float((unsigned)u << 16);
}

// ---------------------------------------------------------------------------
// Bulk f32 -> bf16 convert of 4 tensors (1M elems each).
// ---------------------------------------------------------------------------
__global__ __launch_bounds__(256) void cvt_kernel(
    const float* __restrict__ s0, const float* __restrict__ s1,
    const float* __restrict__ s2, const float* __restrict__ s3,
    unsigned short* __restrict__ d0, unsigned short* __restrict__ d1,
    unsigned short* __restrict__ d2, unsigned short* __restrict__ d3)
{
    const float* s; unsigned short* d;
    switch (blockIdx.y) {
        case 0:  s = s0; d = d0; break;
        case 1:  s = s1; d = d1; break;
        case 2:  s = s2; d = d2; break;
        default: s = s3; d = d3; break;
    }
    const int i = (blockIdx.x * 256 + threadIdx.x) * 8;
    float4 a = *(const float4*)&s[i];
    float4 b = *(const float4*)&s[i + 4];
    short8 o;
    o[0] = (short)f2bf(a.x); o[1] = (short)f2bf(a.y);
    o[2] = (short)f2bf(a.z); o[3] = (short)f2bf(a.w);
    o[4] = (short)f2bf(b.x); o[5] = (short)f2bf(b.y);
    o[6] = (short)f2bf(b.z); o[7] = (short)f2bf(b.w);
    *(short8*)&d[i] = o;
}

// ---------------------------------------------------------------------------
// MFMA NT-GEMM core: C(128 x 128) += A(128 x K)*B(128 x K)^T
// ---------------------------------------------------------------------------
__device__ __forceinline__ void mfma_core128(
    const unsigned short* __restrict__ A, const unsigned short* __restrict__ B,
    int K, int m0, int n0, int t, f32x4 (&acc)[4][4])
{
    constexpr int LDT = 40;
    __shared__ unsigned short As[128 * LDT];
    __shared__ unsigned short Bs[128 * LDT];
    const int row = t >> 2;
    const int kc  = (t & 3) * 8;
    const unsigned short* gA0 = A + (size_t)(m0 + row) * 1024 + kc;
    const unsigned short* gA1 = gA0 + (size_t)64 * 1024;
    unsigned short* sA0 = &As[row * LDT + kc];
    unsigned short* sA1 = sA0 + 64 * LDT;
    const unsigned short* gB0 = B + (size_t)(n0 + row) * 1024 + kc;
    const unsigned short* gB1 = gB0 + (size_t)64 * 1024;
    unsigned short* sB0 = &Bs[row * LDT + kc];
    unsigned short* sB1 = sB0 + 64 * LDT;
    int4 ra0 = *(const int4*)gA0;
    int4 ra1 = *(const int4*)gA1;
    int4 rb0 = *(const int4*)gB0;
    int4 rb1 = *(const int4*)gB1;
    const int lane = t & 63, wid = t >> 6;
    const int wm = (wid & 1) * 64, wn = (wid >> 1) * 64;
    const unsigned short* pa = &As[(wm + (lane & 15)) * LDT + (lane >> 4) * 8];
    const unsigned short* pb = &Bs[(wn + (lane & 15)) * LDT + (lane >> 4) * 8];
    for (int k0 = 0; k0 < K; k0 += 32) {
        *(int4*)sA0 = ra0; *(int4*)sA1 = ra1;
        *(int4*)sB0 = rb0; *(int4*)sB1 = rb1;
        __syncthreads();
        if (k0 + 32 < K) {
            ra0 = *(const int4*)(gA0 + k0 + 32);
            ra1 = *(const int4*)(gA1 + k0 + 32);
            rb0 = *(const int4*)(gB0 + k0 + 32);
            rb1 = *(const int4*)(gB1 + k0 + 32);
        }
        short8 af[4], bfr[4];
#pragma unroll
        for (int mi = 0; mi < 4; ++mi) af[mi]  = *(const short8*)(pa + mi * 16 * LDT);
#pragma unroll
        for (int ni = 0; ni < 4; ++ni) bfr[ni] = *(const short8*)(pb + ni * 16 * LDT);
#pragma unroll
        for (int mi = 0; mi < 4; ++mi)
#pragma unroll
            for (int ni = 0; ni < 4; ++ni)
                acc[mi][ni] = __builtin_amdgcn_mfma_f32_16x16x32_bf16(
                    af[mi], bfr[ni], acc[mi][ni], 0, 0, 0);
        __syncthreads();
    }
}

struct Triples {
    const unsigned short* A[3];
    const unsigned short* B[3];
    unsigned short*       C[3];
    const float*          bias[3];
};

__global__ __launch_bounds__(256) void gemm3_kernel(Triples tr)
{
    const int z  = blockIdx.z;
    const int m0 = blockIdx.y * 128, n0 = blockIdx.x * 128;
    const int t  = threadIdx.x;
    f32x4 acc[4][4];
    const f32x4 z4 = {0.f, 0.f, 0.f, 0.f};
#pragma unroll
    for (int i = 0; i < 4; ++i)
#pragma unroll
        for (int j = 0; j < 4; ++j) acc[i][j] = z4;
    mfma_core128(tr.A[z], tr.B[z], 1024, m0, n0, t, acc);
    const float* bias = tr.bias[z];
    unsigned short* C = tr.C[z];
    const int lane = t & 63, wid = t >> 6;
    const int wm = (wid & 1) * 64, wn = (wid >> 1) * 64;
    const int r0 = (lane >> 4) * 4, cc = lane & 15;
#pragma unroll
    for (int mi = 0; mi < 4; ++mi)
#pragma unroll
        for (int ni = 0; ni < 4; ++ni) {
            const int col = n0 + wn + ni * 16 + cc;
            const float bb = bias ? bias[col] : 0.f;
#pragma unroll
            for (int r = 0; r < 4; ++r) {
                const int rowi = m0 + wm + mi * 16 + r0 + r;
                C[(size_t)rowi * 1024 + col] = f2bf(acc[mi][ni][r] + bb);
            }
        }
}

// ---------------------------------------------------------------------------
// pos via MFMA: logw[n][g][m] = bf16( log(max(relu(emb(n,m)·Wg[g]+bg[g]),1e-6)) )
// ---------------------------------------------------------------------------
__global__ __launch_bounds__(256) void pos_mfma_kernel(
    const float* __restrict__ rois, const float* __restrict__ Wg,
    const float* __restrict__ bg, unsigned short* __restrict__ logw)
{
    __shared__ unsigned short wg_s[16 * 72];
    __shared__ float bg_s[16];
    __shared__ float mbox[1024][4];
    const int t = threadIdx.x;
    if (t < 128) {
        const int gi = t >> 3, c = (t & 7) * 8;
        unsigned short* d = &wg_s[gi * 72 + c];
#pragma unroll
        for (int u = 0; u < 8; ++u) d[u] = f2bf(Wg[gi * 64 + c + u]);
    }
    if (t < 16) bg_s[t] = bg[t];
#pragma unroll
    for (int i = 0; i < 4; ++i) {
        const int m = t + i * 256;
        const float x1 = rois[m * 5 + 1], y1 = rois[m * 5 + 2];
        const float x2 = rois[m * 5 + 3], y2 = rois[m * 5 + 4];
        mbox[m][0] = (x1 + x2) * 0.5f;
        mbox[m][1] = (y1 + y2) * 0.5f;
        mbox[m][2] = x2 - x1 + 1.f;
        mbox[m][3] = y2 - y1 + 1.f;
    }
    const int n = blockIdx.x;
    const float x1 = rois[n * 5 + 1], y1 = rois[n * 5 + 2];
    const float x2 = rois[n * 5 + 3], y2 = rois[n * 5 + 4];
    const float cxn = (x1 + x2) * 0.5f, cyn = (y1 + y2) * 0.5f;
    const float wn = x2 - x1 + 1.f, hn = y2 - y1 + 1.f;
    const float iwn = 1.f / wn, ihn = 1.f / hn;
    const float lwn = __logf(wn), lhn = __logf(hn);
    __syncthreads();

    const int lane = t & 63, w = t >> 6;
    const int g  = lane & 15;
    const int qw = lane >> 4;
    const float coff = (qw & 1) ? 1.5707963268f : 0.f;
    const int f0 = qw >> 1;
    const short8 bf0 = *(const short8*)&wg_s[g * 72 + qw * 8];
    const short8 bf1 = *(const short8*)&wg_s[g * 72 + qw * 8 + 32];
    const float bgv = bg_s[g];
    const float invd[8] = {1.f, 0.42169650342f, 0.1778279410f, 0.07498942093f,
                           0.0316227766f, 0.01333521432f, 0.005623413252f, 0.002371373706f};
    unsigned short* outp = logw + (size_t)n * 16384;

    for (int c = w * 16; c < w * 16 + 16; ++c) {
        const int ma = c * 16 + (lane & 15);
        float4 mb = *(const float4*)&mbox[ma][0];
        float p0 = (f0 == 0)
                 ? __logf(fmaxf(fabsf((cxn - mb.x) * iwn), 1e-3f))
                 : __logf(fmaxf(fabsf((cyn - mb.y) * ihn), 1e-3f));
        float p1 = (f0 == 0) ? (lwn - __logf(mb.z)) : (lhn - __logf(mb.w));
        p0 *= 100.f; p1 *= 100.f;
        short8 af0, af1;
#pragma unroll
        for (int rr = 0; rr < 8; ++rr) {
            af0[rr] = (short)f2bf(__sinf(p0 * invd[rr] + coff));
            af1[rr] = (short)f2bf(__sinf(p1 * invd[rr] + coff));
        }
        f32x4 acc = {0.f, 0.f, 0.f, 0.f};
        acc = __builtin_amdgcn_mfma_f32_16x16x32_bf16(af0, bf0, acc, 0, 0, 0);
        acc = __builtin_amdgcn_mfma_f32_16x16x32_bf16(af1, bf1, acc, 0, 0, 0);
        unsigned short o[4];
#pragma unroll
        for (int r = 0; r < 4; ++r)
            o[r] = f2bf(__logf(fmaxf(acc[r] + bgv, 1e-6f)));
        const unsigned lo = (unsigned)o[0] | ((unsigned)o[1] << 16);
        const unsigned hi = (unsigned)o[2] | ((unsigned)o[3] << 16);
        *(uint2*)&outp[(size_t)g * 1024 + c * 16 + qw * 4] = make_uint2(lo, hi);
    }
}

// ---------------------------------------------------------------------------
// Fused aff + logw + softmax + rel, FLASH style.
// Block = (n-tile 16 = blockIdx.x, g = blockIdx.y), 4 waves.
// Wave w owns m in [w*256, (w+1)*256), 8 chunks of 32 m:
//   S = q.k^T (MFMA, frags from L2) -> +logw, online max (shfl) -> P bf16
//   via wave-private padded LDS tile -> PV MFMA into 16 reg accumulators.
// Cross-wave combine at the end (one barrier).
// ---------------------------------------------------------------------------
__global__ __launch_bounds__(256) void attn_kernel(
    const unsigned short* __restrict__ qb, const unsigned short* __restrict__ kb,
    const unsigned short* __restrict__ logw, const unsigned short* __restrict__ FWt,
    const float* __restrict__ bv, float* __restrict__ out)
{
    __shared__ unsigned short qs[16 * 72];        // 2.3 KB
    __shared__ unsigned short Pbuf[4][16 * 40];   // 5 KB, wave-private tiles
    __shared__ float Ored[4][16][68];             // 17.4 KB
    __shared__ float mw_s[4][16], sw_s[4][16];

    const int t  = threadIdx.x;
    const int n0 = blockIdx.x * 16;
    const int g  = blockIdx.y;
    const int lane = t & 63, w = t >> 6;
    const int qw = lane >> 4, lx = lane & 15;

    if (t < 128) {
        const int row = t >> 3, c = (t & 7) * 8;
        *(int4*)&qs[row * 72 + c] =
            *(const int4*)&qb[(size_t)(n0 + row) * 1024 + g * 64 + c];
    }
    __syncthreads();

    const short8 aq0 = *(const short8*)&qs[lx * 72 + qw * 8];
    const short8 aq1 = *(const short8*)&qs[lx * 72 + qw * 8 + 32];
    unsigned short* Pw = Pbuf[w];

    f32x4 acc[4];
    const f32x4 z4 = {0.f, 0.f, 0.f, 0.f};
#pragma unroll
    for (int nb = 0; nb < 4; ++nb) acc[nb] = z4;
    float mrow[4] = {-1e30f, -1e30f, -1e30f, -1e30f};
    float srow[4] = {0.f, 0.f, 0.f, 0.f};

    const unsigned short* lwb =
        logw + (size_t)n0 * 16384 + (size_t)g * 1024;   // + row*16384 + m

    for (int cc2 = 0; cc2 < 8; ++cc2) {
        const int m0 = w * 256 + cc2 * 32;
        // ---- S for two 16-m tiles (K frags from L2) ----
        f32x4 s0 = z4, s1 = z4;
        {
            const unsigned short* kp0 = &kb[(size_t)(m0 + lx) * 1024 + g * 64 + qw * 8];
            const unsigned short* kp1 = kp0 + 16 * 1024;
            short8 b00 = *(const short8*)kp0;
            short8 b01 = *(const short8*)(kp0 + 32);
            short8 b10 = *(const short8*)kp1;
            short8 b11 = *(const short8*)(kp1 + 32);
            s0 = __builtin_amdgcn_mfma_f32_16x16x32_bf16(aq0, b00, s0, 0, 0, 0);
            s0 = __builtin_amdgcn_mfma_f32_16x16x32_bf16(aq1, b01, s0, 0, 0, 0);
            s1 = __builtin_amdgcn_mfma_f32_16x16x32_bf16(aq0, b10, s1, 0, 0, 0);
            s1 = __builtin_amdgcn_mfma_f32_16x16x32_bf16(aq1, b11, s1, 0, 0, 0);
        }
        // ---- v = S*0.125 + logw; chunk max per row ----
        float v0[4], v1[4], cm[4];
#pragma unroll
        for (int r = 0; r < 4; ++r) {
            const unsigned short* lp = lwb + (size_t)(qw * 4 + r) * 16384 + m0 + lx;
            v0[r] = s0[r] * 0.125f + bf2f(lp[0]);
            v1[r] = s1[r] * 0.125f + bf2f(lp[16]);
            cm[r] = fmaxf(v0[r], v1[r]);
        }
#pragma unroll
        for (int o = 1; o < 16; o <<= 1) {
#pragma unroll
            for (int r = 0; r < 4; ++r)
                cm[r] = fmaxf(cm[r], __shfl_xor(cm[r], o));
        }
        // ---- online rescale ----
#pragma unroll
        for (int r = 0; r < 4; ++r) {
            const float nm = fmaxf(mrow[r], cm[r]);
            const float f  = __expf(mrow[r] - nm);
            mrow[r] = nm;
            srow[r] *= f;
#pragma unroll
            for (int nb = 0; nb < 4; ++nb) acc[nb][r] *= f;
        }
        // ---- P = exp(v - m), bf16 into wave tile ----
#pragma unroll
        for (int r = 0; r < 4; ++r) {
            const float p0 = __expf(v0[r] - mrow[r]);
            const float p1 = __expf(v1[r] - mrow[r]);
            srow[r] += p0 + p1;
            Pw[(qw * 4 + r) * 40 + lx]      = f2bf(p0);
            Pw[(qw * 4 + r) * 40 + 16 + lx] = f2bf(p1);
        }
        // wave-synchronous LDS: DS ops from one wave execute in order;
        // compiler keeps order (may-alias) and inserts lgkmcnt.
        const short8 ap = *(const short8*)&Pw[lx * 40 + qw * 8];
        // ---- PV ----
#pragma unroll
        for (int nb = 0; nb < 4; ++nb) {
            const short8 bf = *(const short8*)
                &FWt[(size_t)(g * 64 + nb * 16 + lx) * 1024 + m0 + qw * 8];
            acc[nb] = __builtin_amdgcn_mfma_f32_16x16x32_bf16(ap, bf, acc[nb], 0, 0, 0);
        }
    }

    // ---- per-wave epilogue: reduce srow across the 16 lx lanes ----
#pragma unroll
    for (int o = 1; o < 16; o <<= 1) {
#pragma unroll
        for (int r = 0; r < 4; ++r)
            srow[r] += __shfl_xor(srow[r], o);
    }
#pragma unroll
    for (int nb = 0; nb < 4; ++nb)
#pragma unroll
        for (int r = 0; r < 4; ++r)
            Ored[w][qw * 4 + r][nb * 16 + lx] = acc[nb][r];
    if (lx == 0) {
#pragma unroll
        for (int r = 0; r < 4; ++r) {
            mw_s[w][qw * 4 + r] = mrow[r];
            sw_s[w][qw * 4 + r] = srow[r];
        }
    }
    __syncthreads();

    // ---- cross-wave combine: thread t -> (n = t>>4, d quad = (t&15)*4) ----
    {
        const int nn = t >> 4, d0 = (t & 15) * 4;
        const float m0w = mw_s[0][nn], m1w = mw_s[1][nn];
        const float m2w = mw_s[2][nn], m3w = mw_s[3][nn];
        const float M = fmaxf(fmaxf(m0w, m1w), fmaxf(m2w, m3w));
        const float f0w = __expf(m0w - M), f1w = __expf(m1w - M);
        const float f2w = __expf(m2w - M), f3w = __expf(m3w - M);
        const float stot = sw_s[0][nn] * f0w + sw_s[1][nn] * f1w
                         + sw_s[2][nn] * f2w + sw_s[3][nn] * f3w;
        float4 o0 = *(const float4*)&Ored[0][nn][d0];
        float4 o1 = *(const float4*)&Ored[1][nn][d0];
        float4 o2 = *(const float4*)&Ored[2][nn][d0];
        float4 o3 = *(const float4*)&Ored[3][nn][d0];
        const float inv = 1.f / stot;
        float4 b4 = *(const float4*)&bv[g * 64 + d0];
        float4 o;
        o.x = (o0.x * f0w + o1.x * f1w + o2.x * f2w + o3.x * f3w) * inv + b4.x;
        o.y = (o0.y * f0w + o1.y * f1w + o2.y * f2w + o3.y * f3w) * inv + b4.y;
        o.z = (o0.z * f0w + o1.z * f1w + o2.z * f2w + o3.z * f3w) * inv + b4.z;
        o.w = (o0.w * f0w + o1.w * f1w + o2.w * f2w + o3.w * f3w) * inv + b4.w;
        *(float4*)&out[(size_t)(n0 + nn) * 1024 + g * 64 + d0] = o;
    }
}

extern "C" void kernel_launch(void* const* d_in, const int* in_sizes, int n_in,
                              void* d_out, int out_size, void* d_ws, size_t ws_size,
                              hipStream_t stream)
{
    const float* feats = (const float*)d_in[0];
    const float* rois  = (const float*)d_in[1];
    const float* Wq    = (const float*)d_in[2];
    const float* bq    = (const float*)d_in[3];
    const float* Wk    = (const float*)d_in[4];
    const float* bk    = (const float*)d_in[5];
    const float* Wg    = (const float*)d_in[6];
    const float* bg    = (const float*)d_in[7];
    const float* Wv    = (const float*)d_in[8];
    const float* bv    = (const float*)d_in[9];
    float* out = (float*)d_out;

    char* wsb = (char*)d_ws;
    unsigned short* logwb  = (unsigned short*)wsb;                 // 32MB after gemm3
    unsigned short* Wqb    = (unsigned short*)(wsb + (0ull  << 20));
    unsigned short* Wkb    = (unsigned short*)(wsb + (2ull  << 20));
    unsigned short* Wvb    = (unsigned short*)(wsb + (4ull  << 20));
    unsigned short* featsb = (unsigned short*)(wsb + (64ull << 20));
    unsigned short* qb     = (unsigned short*)(wsb + (66ull << 20));
    unsigned short* kb     = (unsigned short*)(wsb + (68ull << 20));
    unsigned short* FWtb   = (unsigned short*)(wsb + (70ull << 20));

    cvt_kernel<<<dim3(512, 4), 256, 0, stream>>>(feats, Wq, Wk, Wv,
                                                 featsb, Wqb, Wkb, Wvb);

    Triples tr;
    tr.A[0] = featsb; tr.B[0] = Wqb;    tr.C[0] = qb;   tr.bias[0] = bq;
    tr.A[1] = featsb; tr.B[1] = Wkb;    tr.C[1] = kb;   tr.bias[1] = bk;
    tr.A[2] = Wvb;    tr.B[2] = featsb; tr.C[2] = FWtb; tr.bias[2] = nullptr;
    gemm3_kernel<<<dim3(8, 8, 3), 256, 0, stream>>>(tr);

    pos_mfma_kernel<<<1024, 256, 0, stream>>>(rois, Wg, bg, logwb);

    attn_kernel<<<dim3(64, 16), 256, 0, stream>>>(qb, kb, logwb, FWtb, bv, out);
}

// Round 5
// 98.688 us; speedup vs baseline: 3.4145x; 1.0295x over previous
//
#include <hip/hip_runtime.h>
#include <math.h>

#define N_ROIS 1024
#define C_DIM  1024

typedef __attribute__((ext_vector_type(8))) short short8;
typedef __attribute__((ext_vector_type(4))) float f32x4;

__device__ __forceinline__ unsigned short f2bf(float x) {
    union { float f; unsigned u; } v; v.f = x;
    unsigned r = v.u + 0x7fffu + ((v.u >> 16) & 1u);
    return (unsigned short)(r >> 16);
}
__device__ __forceinline__ float bf2f(unsigned short u) {
    return __uint_as_float((unsigned)u << 16);
}

// ---------------------------------------------------------------------------
// Bulk f32 -> bf16 convert of 4 tensors (1M elems each).
// ---------------------------------------------------------------------------
__global__ __launch_bounds__(256) void cvt_kernel(
    const float* __restrict__ s0, const float* __restrict__ s1,
    const float* __restrict__ s2, const float* __restrict__ s3,
    unsigned short* __restrict__ d0, unsigned short* __restrict__ d1,
    unsigned short* __restrict__ d2, unsigned short* __restrict__ d3)
{
    const float* s; unsigned short* d;
    switch (blockIdx.y) {
        case 0:  s = s0; d = d0; break;
        case 1:  s = s1; d = d1; break;
        case 2:  s = s2; d = d2; break;
        default: s = s3; d = d3; break;
    }
    const int i = (blockIdx.x * 256 + threadIdx.x) * 8;
    float4 a = *(const float4*)&s[i];
    float4 b = *(const float4*)&s[i + 4];
    short8 o;
    o[0] = (short)f2bf(a.x); o[1] = (short)f2bf(a.y);
    o[2] = (short)f2bf(a.z); o[3] = (short)f2bf(a.w);
    o[4] = (short)f2bf(b.x); o[5] = (short)f2bf(b.y);
    o[6] = (short)f2bf(b.z); o[7] = (short)f2bf(b.w);
    *(short8*)&d[i] = o;
}

// ---------------------------------------------------------------------------
// MFMA NT-GEMM core: C(128 x 128) += A(128 x K)*B(128 x K)^T
// ---------------------------------------------------------------------------
__device__ __forceinline__ void mfma_core128(
    const unsigned short* __restrict__ A, const unsigned short* __restrict__ B,
    int K, int m0, int n0, int t, f32x4 (&acc)[4][4])
{
    constexpr int LDT = 40;
    __shared__ unsigned short As[128 * LDT];
    __shared__ unsigned short Bs[128 * LDT];
    const int row = t >> 2;
    const int kc  = (t & 3) * 8;
    const unsigned short* gA0 = A + (size_t)(m0 + row) * 1024 + kc;
    const unsigned short* gA1 = gA0 + (size_t)64 * 1024;
    unsigned short* sA0 = &As[row * LDT + kc];
    unsigned short* sA1 = sA0 + 64 * LDT;
    const unsigned short* gB0 = B + (size_t)(n0 + row) * 1024 + kc;
    const unsigned short* gB1 = gB0 + (size_t)64 * 1024;
    unsigned short* sB0 = &Bs[row * LDT + kc];
    unsigned short* sB1 = sB0 + 64 * LDT;
    int4 ra0 = *(const int4*)gA0;
    int4 ra1 = *(const int4*)gA1;
    int4 rb0 = *(const int4*)gB0;
    int4 rb1 = *(const int4*)gB1;
    const int lane = t & 63, wid = t >> 6;
    const int wm = (wid & 1) * 64, wn = (wid >> 1) * 64;
    const unsigned short* pa = &As[(wm + (lane & 15)) * LDT + (lane >> 4) * 8];
    const unsigned short* pb = &Bs[(wn + (lane & 15)) * LDT + (lane >> 4) * 8];
    for (int k0 = 0; k0 < K; k0 += 32) {
        *(int4*)sA0 = ra0; *(int4*)sA1 = ra1;
        *(int4*)sB0 = rb0; *(int4*)sB1 = rb1;
        __syncthreads();
        if (k0 + 32 < K) {
            ra0 = *(const int4*)(gA0 + k0 + 32);
            ra1 = *(const int4*)(gA1 + k0 + 32);
            rb0 = *(const int4*)(gB0 + k0 + 32);
            rb1 = *(const int4*)(gB1 + k0 + 32);
        }
        short8 af[4], bfr[4];
#pragma unroll
        for (int mi = 0; mi < 4; ++mi) af[mi]  = *(const short8*)(pa + mi * 16 * LDT);
#pragma unroll
        for (int ni = 0; ni < 4; ++ni) bfr[ni] = *(const short8*)(pb + ni * 16 * LDT);
#pragma unroll
        for (int mi = 0; mi < 4; ++mi)
#pragma unroll
            for (int ni = 0; ni < 4; ++ni)
                acc[mi][ni] = __builtin_amdgcn_mfma_f32_16x16x32_bf16(
                    af[mi], bfr[ni], acc[mi][ni], 0, 0, 0);
        __syncthreads();
    }
}

struct Triples {
    const unsigned short* A[3];
    const unsigned short* B[3];
    unsigned short*       C[3];
    const float*          bias[3];
};

__global__ __launch_bounds__(256) void gemm3_kernel(Triples tr)
{
    const int z  = blockIdx.z;
    const int m0 = blockIdx.y * 128, n0 = blockIdx.x * 128;
    const int t  = threadIdx.x;
    f32x4 acc[4][4];
    const f32x4 z4 = {0.f, 0.f, 0.f, 0.f};
#pragma unroll
    for (int i = 0; i < 4; ++i)
#pragma unroll
        for (int j = 0; j < 4; ++j) acc[i][j] = z4;
    mfma_core128(tr.A[z], tr.B[z], 1024, m0, n0, t, acc);
    const float* bias = tr.bias[z];
    unsigned short* C = tr.C[z];
    const float sc = (z == 0) ? 0.125f : 1.0f;   // fold softmax scale into q
    const int lane = t & 63, wid = t >> 6;
    const int wm = (wid & 1) * 64, wn = (wid >> 1) * 64;
    const int r0 = (lane >> 4) * 4, cc = lane & 15;
#pragma unroll
    for (int mi = 0; mi < 4; ++mi)
#pragma unroll
        for (int ni = 0; ni < 4; ++ni) {
            const int col = n0 + wn + ni * 16 + cc;
            const float bb = bias ? bias[col] : 0.f;
#pragma unroll
            for (int r = 0; r < 4; ++r) {
                const int rowi = m0 + wm + mi * 16 + r0 + r;
                C[(size_t)rowi * 1024 + col] = f2bf((acc[mi][ni][r] + bb) * sc);
            }
        }
}

// ---------------------------------------------------------------------------
// pos via MFMA: logw[n][g][m] = bf16( log(max(relu(emb(n,m)·Wg[g]+bg[g]),1e-6)) )
// ---------------------------------------------------------------------------
__global__ __launch_bounds__(256) void pos_mfma_kernel(
    const float* __restrict__ rois, const float* __restrict__ Wg,
    const float* __restrict__ bg, unsigned short* __restrict__ logw)
{
    __shared__ unsigned short wg_s[16 * 72];
    __shared__ float bg_s[16];
    __shared__ float mbox[1024][4];
    const int t = threadIdx.x;
    if (t < 128) {
        const int gi = t >> 3, c = (t & 7) * 8;
        unsigned short* d = &wg_s[gi * 72 + c];
#pragma unroll
        for (int u = 0; u < 8; ++u) d[u] = f2bf(Wg[gi * 64 + c + u]);
    }
    if (t < 16) bg_s[t] = bg[t];
#pragma unroll
    for (int i = 0; i < 4; ++i) {
        const int m = t + i * 256;
        const float x1 = rois[m * 5 + 1], y1 = rois[m * 5 + 2];
        const float x2 = rois[m * 5 + 3], y2 = rois[m * 5 + 4];
        mbox[m][0] = (x1 + x2) * 0.5f;
        mbox[m][1] = (y1 + y2) * 0.5f;
        mbox[m][2] = x2 - x1 + 1.f;
        mbox[m][3] = y2 - y1 + 1.f;
    }
    const int n = blockIdx.x;
    const float x1 = rois[n * 5 + 1], y1 = rois[n * 5 + 2];
    const float x2 = rois[n * 5 + 3], y2 = rois[n * 5 + 4];
    const float cxn = (x1 + x2) * 0.5f, cyn = (y1 + y2) * 0.5f;
    const float wn = x2 - x1 + 1.f, hn = y2 - y1 + 1.f;
    const float iwn = 1.f / wn, ihn = 1.f / hn;
    const float lwn = __logf(wn), lhn = __logf(hn);
    __syncthreads();

    const int lane = t & 63, w = t >> 6;
    const int g  = lane & 15;
    const int qw = lane >> 4;
    const float coff = (qw & 1) ? 1.5707963268f : 0.f;
    const int f0 = qw >> 1;
    const short8 bf0 = *(const short8*)&wg_s[g * 72 + qw * 8];
    const short8 bf1 = *(const short8*)&wg_s[g * 72 + qw * 8 + 32];
    const float bgv = bg_s[g];
    const float invd[8] = {1.f, 0.42169650342f, 0.1778279410f, 0.07498942093f,
                           0.0316227766f, 0.01333521432f, 0.005623413252f, 0.002371373706f};
    unsigned short* outp = logw + (size_t)n * 16384;

    for (int c = w * 16; c < w * 16 + 16; ++c) {
        const int ma = c * 16 + (lane & 15);
        float4 mb = *(const float4*)&mbox[ma][0];
        float p0 = (f0 == 0)
                 ? __logf(fmaxf(fabsf((cxn - mb.x) * iwn), 1e-3f))
                 : __logf(fmaxf(fabsf((cyn - mb.y) * ihn), 1e-3f));
        float p1 = (f0 == 0) ? (lwn - __logf(mb.z)) : (lhn - __logf(mb.w));
        p0 *= 100.f; p1 *= 100.f;
        short8 af0, af1;
#pragma unroll
        for (int rr = 0; rr < 8; ++rr) {
            af0[rr] = (short)f2bf(__sinf(p0 * invd[rr] + coff));
            af1[rr] = (short)f2bf(__sinf(p1 * invd[rr] + coff));
        }
        f32x4 acc = {0.f, 0.f, 0.f, 0.f};
        acc = __builtin_amdgcn_mfma_f32_16x16x32_bf16(af0, bf0, acc, 0, 0, 0);
        acc = __builtin_amdgcn_mfma_f32_16x16x32_bf16(af1, bf1, acc, 0, 0, 0);
        unsigned short o[4];
#pragma unroll
        for (int r = 0; r < 4; ++r)
            o[r] = f2bf(__logf(fmaxf(acc[r] + bgv, 1e-6f)));
        const unsigned lo = (unsigned)o[0] | ((unsigned)o[1] << 16);
        const unsigned hi = (unsigned)o[2] | ((unsigned)o[3] << 16);
        *(uint2*)&outp[(size_t)g * 1024 + c * 16 + qw * 4] = make_uint2(lo, hi);
    }
}

// ---------------------------------------------------------------------------
// Fused aff + logw + softmax + rel, FLASH style, swapped-operand + pipelined.
// Block = (16-row n-tile, g), 4 waves; wave w owns m in [w*256,(w+1)*256),
// 4 iterations of 64 m.
//   S = mfma(K, Q)  -> D[m][n]: lane (qw,lx) holds n=lx, m=mt+qw*4+r
//     => logw loads are 4x8B/iter, row-max = 2 shfl_xor, P writes 8B packed.
//   PV = mfma(FW, P) -> D[d][n]: acc rows n=lx => rescale uses lane's own f.
//   K frags + logw double-buffered one iteration ahead (register prefetch).
// ---------------------------------------------------------------------------
#define PPAD 88

__global__ __launch_bounds__(256) void attn_kernel(
    const unsigned short* __restrict__ qb, const unsigned short* __restrict__ kb,
    const unsigned short* __restrict__ logw, const unsigned short* __restrict__ FWt,
    const float* __restrict__ bv, float* __restrict__ out)
{
    __shared__ unsigned short qs[16 * 72];        // 2.3 KB
    __shared__ unsigned short Pbuf[4][16 * PPAD]; // 11.3 KB wave-private P tiles
    __shared__ float Ored[4][16][68];             // 17.4 KB
    __shared__ float mw_s[4][16], sw_s[4][16];

    const int t  = threadIdx.x;
    const int n0 = blockIdx.x * 16;
    const int g  = blockIdx.y;
    const int lane = t & 63, w = t >> 6;
    const int qw = lane >> 4, lx = lane & 15;

    if (t < 128) {
        const int row = t >> 3, c = (t & 7) * 8;
        *(int4*)&qs[row * 72 + c] =
            *(const int4*)&qb[(size_t)(n0 + row) * 1024 + g * 64 + c];
    }
    __syncthreads();

    const short8 bq0 = *(const short8*)&qs[lx * 72 + qw * 8];
    const short8 bq1 = *(const short8*)&qs[lx * 72 + qw * 8 + 32];
    unsigned short* Pw = Pbuf[w];

    f32x4 acc[4];
    const f32x4 z4 = {0.f, 0.f, 0.f, 0.f};
#pragma unroll
    for (int nb = 0; nb < 4; ++nb) acc[nb] = z4;
    float mrow = -1e30f, srow = 0.f;

    const unsigned short* kbase = kb + g * 64 + qw * 8;                       // + m*1024
    const unsigned short* fbase = FWt + (size_t)(g * 64 + lx) * 1024 + qw * 8; // + nb*16384 + moff
    const unsigned short* lwp   = logw + (size_t)(n0 + lx) * 16384 + g * 1024
                                + qw * 4 + w * 256;                            // + it*64 + tt*16

    short8 kf[2][4][2];
    uint2  lwr[2][4];
#pragma unroll
    for (int tt = 0; tt < 4; ++tt) {
        const unsigned short* kp = kbase + (size_t)(w * 256 + tt * 16 + lx) * 1024;
        kf[0][tt][0] = *(const short8*)kp;
        kf[0][tt][1] = *(const short8*)(kp + 32);
        lwr[0][tt] = *(const uint2*)(lwp + tt * 16);
    }

#pragma unroll
    for (int it = 0; it < 4; ++it) {
        const int m0  = w * 256 + it * 64;
        const int cur = it & 1, nxt = cur ^ 1;

        // ---- prefetch next iteration's K frags + logw ----
        if (it < 3) {
#pragma unroll
            for (int tt = 0; tt < 4; ++tt) {
                const unsigned short* kp = kbase + (size_t)(m0 + 64 + tt * 16 + lx) * 1024;
                kf[nxt][tt][0] = *(const short8*)kp;
                kf[nxt][tt][1] = *(const short8*)(kp + 32);
                lwr[nxt][tt] = *(const uint2*)(lwp + it * 64 + 64 + tt * 16);
            }
        }

        // ---- S = mfma(K, Q): D[m][n] ----
        f32x4 s[4];
#pragma unroll
        for (int tt = 0; tt < 4; ++tt) {
            f32x4 z = z4;
            z = __builtin_amdgcn_mfma_f32_16x16x32_bf16(kf[cur][tt][0], bq0, z, 0, 0, 0);
            s[tt] = __builtin_amdgcn_mfma_f32_16x16x32_bf16(kf[cur][tt][1], bq1, z, 0, 0, 0);
        }

        // ---- FW frags for PV (L2-resident; issued early for cover) ----
        short8 fw[2][4];
#pragma unroll
        for (int ks = 0; ks < 2; ++ks)
#pragma unroll
            for (int nb = 0; nb < 4; ++nb)
                fw[ks][nb] = *(const short8*)(fbase + (size_t)nb * 16384 + m0 + ks * 32);

        // ---- v = S + logw; chunk max (lane has n=lx, 16 m-values) ----
        float v[4][4];
        float cmx = -1e30f;
#pragma unroll
        for (int tt = 0; tt < 4; ++tt) {
            const uint2 lw = lwr[cur][tt];
            v[tt][0] = s[tt][0] + bf2f((unsigned short)(lw.x & 0xffff));
            v[tt][1] = s[tt][1] + bf2f((unsigned short)(lw.x >> 16));
            v[tt][2] = s[tt][2] + bf2f((unsigned short)(lw.y & 0xffff));
            v[tt][3] = s[tt][3] + bf2f((unsigned short)(lw.y >> 16));
            cmx = fmaxf(cmx, fmaxf(fmaxf(v[tt][0], v[tt][1]), fmaxf(v[tt][2], v[tt][3])));
        }
        cmx = fmaxf(cmx, __shfl_xor(cmx, 16));
        cmx = fmaxf(cmx, __shfl_xor(cmx, 32));

        // ---- online rescale (per-lane f: acc rows are n=lx) ----
        const float nm = fmaxf(mrow, cmx);
        const float f  = __expf(mrow - nm);
        mrow = nm;
        srow *= f;
#pragma unroll
        for (int nb = 0; nb < 4; ++nb) {
            acc[nb][0] *= f; acc[nb][1] *= f;
            acc[nb][2] *= f; acc[nb][3] *= f;
        }

        // ---- P = exp(v - m) -> packed 8B LDS writes ----
#pragma unroll
        for (int tt = 0; tt < 4; ++tt) {
            const float p0 = __expf(v[tt][0] - nm);
            const float p1 = __expf(v[tt][1] - nm);
            const float p2 = __expf(v[tt][2] - nm);
            const float p3 = __expf(v[tt][3] - nm);
            srow += (p0 + p1) + (p2 + p3);
            uint2 pk;
            pk.x = (unsigned)f2bf(p0) | ((unsigned)f2bf(p1) << 16);
            pk.y = (unsigned)f2bf(p2) | ((unsigned)f2bf(p3) << 16);
            *(uint2*)&Pw[lx * PPAD + tt * 16 + qw * 4] = pk;
        }

        // ---- PV = mfma(FW, P): D[d][n] ----
#pragma unroll
        for (int ks = 0; ks < 2; ++ks) {
            const short8 ap = *(const short8*)&Pw[lx * PPAD + ks * 32 + qw * 8];
#pragma unroll
            for (int nb = 0; nb < 4; ++nb)
                acc[nb] = __builtin_amdgcn_mfma_f32_16x16x32_bf16(fw[ks][nb], ap, acc[nb], 0, 0, 0);
        }
    }

    // ---- per-wave epilogue ----
    srow += __shfl_xor(srow, 16);
    srow += __shfl_xor(srow, 32);
#pragma unroll
    for (int nb = 0; nb < 4; ++nb)
#pragma unroll
        for (int r = 0; r < 4; ++r)
            Ored[w][lx][nb * 16 + qw * 4 + r] = acc[nb][r];
    if (lane < 16) {
        mw_s[w][lx] = mrow;
        sw_s[w][lx] = srow;
    }
    __syncthreads();

    // ---- cross-wave combine ----
    {
        const int nn = t >> 4, d0 = (t & 15) * 4;
        const float m0w = mw_s[0][nn], m1w = mw_s[1][nn];
        const float m2w = mw_s[2][nn], m3w = mw_s[3][nn];
        const float M = fmaxf(fmaxf(m0w, m1w), fmaxf(m2w, m3w));
        const float f0w = __expf(m0w - M), f1w = __expf(m1w - M);
        const float f2w = __expf(m2w - M), f3w = __expf(m3w - M);
        const float stot = sw_s[0][nn] * f0w + sw_s[1][nn] * f1w
                         + sw_s[2][nn] * f2w + sw_s[3][nn] * f3w;
        float4 o0 = *(const float4*)&Ored[0][nn][d0];
        float4 o1 = *(const float4*)&Ored[1][nn][d0];
        float4 o2 = *(const float4*)&Ored[2][nn][d0];
        float4 o3 = *(const float4*)&Ored[3][nn][d0];
        const float inv = 1.f / stot;
        float4 b4 = *(const float4*)&bv[g * 64 + d0];
        float4 o;
        o.x = (o0.x * f0w + o1.x * f1w + o2.x * f2w + o3.x * f3w) * inv + b4.x;
        o.y = (o0.y * f0w + o1.y * f1w + o2.y * f2w + o3.y * f3w) * inv + b4.y;
        o.z = (o0.z * f0w + o1.z * f1w + o2.z * f2w + o3.z * f3w) * inv + b4.z;
        o.w = (o0.w * f0w + o1.w * f1w + o2.w * f2w + o3.w * f3w) * inv + b4.w;
        *(float4*)&out[(size_t)(n0 + nn) * 1024 + g * 64 + d0] = o;
    }
}

extern "C" void kernel_launch(void* const* d_in, const int* in_sizes, int n_in,
                              void* d_out, int out_size, void* d_ws, size_t ws_size,
                              hipStream_t stream)
{
    const float* feats = (const float*)d_in[0];
    const float* rois  = (const float*)d_in[1];
    const float* Wq    = (const float*)d_in[2];
    const float* bq    = (const float*)d_in[3];
    const float* Wk    = (const float*)d_in[4];
    const float* bk    = (const float*)d_in[5];
    const float* Wg    = (const float*)d_in[6];
    const float* bg    = (const float*)d_in[7];
    const float* Wv    = (const float*)d_in[8];
    const float* bv    = (const float*)d_in[9];
    float* out = (float*)d_out;

    char* wsb = (char*)d_ws;
    unsigned short* logwb  = (unsigned short*)wsb;                 // 32MB after gemm3
    unsigned short* Wqb    = (unsigned short*)(wsb + (0ull  << 20));
    unsigned short* Wkb    = (unsigned short*)(wsb + (2ull  << 20));
    unsigned short* Wvb    = (unsigned short*)(wsb + (4ull  << 20));
    unsigned short* featsb = (unsigned short*)(wsb + (64ull << 20));
    unsigned short* qb     = (unsigned short*)(wsb + (66ull << 20));
    unsigned short* kb     = (unsigned short*)(wsb + (68ull << 20));
    unsigned short* FWtb   = (unsigned short*)(wsb + (70ull << 20));

    cvt_kernel<<<dim3(512, 4), 256, 0, stream>>>(feats, Wq, Wk, Wv,
                                                 featsb, Wqb, Wkb, Wvb);

    Triples tr;
    tr.A[0] = featsb; tr.B[0] = Wqb;    tr.C[0] = qb;   tr.bias[0] = bq;
    tr.A[1] = featsb; tr.B[1] = Wkb;    tr.C[1] = kb;   tr.bias[1] = bk;
    tr.A[2] = Wvb;    tr.B[2] = featsb; tr.C[2] = FWtb; tr.bias[2] = nullptr;
    gemm3_kernel<<<dim3(8, 8, 3), 256, 0, stream>>>(tr);

    pos_mfma_kernel<<<1024, 256, 0, stream>>>(rois, Wg, bg, logwb);

    attn_kernel<<<dim3(64, 16), 256, 0, stream>>>(qb, kb, logwb, FWtb, bv, out);
}

// Round 6
// 80.052 us; speedup vs baseline: 4.2094x; 1.2328x over previous
//
#include <hip/hip_runtime.h>
#include <math.h>

#define N_ROIS 1024
#define C_DIM  1024

typedef __attribute__((ext_vector_type(8))) short short8;
typedef __attribute__((ext_vector_type(4))) float f32x4;

__device__ __forceinline__ unsigned short f2bf(float x) {
    union { float f; unsigned u; } v; v.f = x;
    unsigned r = v.u + 0x7fffu + ((v.u >> 16) & 1u);
    return (unsigned short)(r >> 16);
}
__device__ __forceinline__ float bf2f(unsigned short u) {
    return __uint_as_float((unsigned)u << 16);
}

// ---------------------------------------------------------------------------
// Bulk f32 -> bf16 convert of 4 tensors (1M elems each).
// ---------------------------------------------------------------------------
__global__ __launch_bounds__(256) void cvt_kernel(
    const float* __restrict__ s0, const float* __restrict__ s1,
    const float* __restrict__ s2, const float* __restrict__ s3,
    unsigned short* __restrict__ d0, unsigned short* __restrict__ d1,
    unsigned short* __restrict__ d2, unsigned short* __restrict__ d3)
{
    const float* s; unsigned short* d;
    switch (blockIdx.y) {
        case 0:  s = s0; d = d0; break;
        case 1:  s = s1; d = d1; break;
        case 2:  s = s2; d = d2; break;
        default: s = s3; d = d3; break;
    }
    const int i = (blockIdx.x * 256 + threadIdx.x) * 8;
    float4 a = *(const float4*)&s[i];
    float4 b = *(const float4*)&s[i + 4];
    short8 o;
    o[0] = (short)f2bf(a.x); o[1] = (short)f2bf(a.y);
    o[2] = (short)f2bf(a.z); o[3] = (short)f2bf(a.w);
    o[4] = (short)f2bf(b.x); o[5] = (short)f2bf(b.y);
    o[6] = (short)f2bf(b.z); o[7] = (short)f2bf(b.w);
    *(short8*)&d[i] = o;
}

struct Triples {
    const unsigned short* A[3];
    const unsigned short* B[3];
    unsigned short*       C[3];
    const float*          bias[3];
};

// ---------------------------------------------------------------------------
// prep_kernel: flat grid. Blocks [0,192): the three 1024^3 NT GEMMs
// (q [x0.125 folded], k, FWt). Blocks [192,1216): pos -> logw, overlapped
// with the GEMMs on the same dispatch (MFMA-bound + VALU/trans-bound mix).
// ---------------------------------------------------------------------------
__global__ __launch_bounds__(256) void prep_kernel(
    Triples tr, const float* __restrict__ rois, const float* __restrict__ Wg,
    const float* __restrict__ bg, unsigned short* __restrict__ logw)
{
    __shared__ __align__(16) char smem[20480];
    const int bx = blockIdx.x;
    const int t  = threadIdx.x;

    if (bx < 192) {
        // ================= GEMM path =================
        constexpr int LDT = 40;
        unsigned short* As = (unsigned short*)smem;       // 128*40
        unsigned short* Bs = As + 128 * LDT;              // 128*40
        const int z   = bx >> 6;
        const int rem = bx & 63;
        const int m0 = (rem >> 3) * 128, n0 = (rem & 7) * 128;
        const unsigned short* A = tr.A[z];
        const unsigned short* B = tr.B[z];
        f32x4 acc[4][4];
        const f32x4 z4 = {0.f, 0.f, 0.f, 0.f};
#pragma unroll
        for (int i = 0; i < 4; ++i)
#pragma unroll
            for (int j = 0; j < 4; ++j) acc[i][j] = z4;

        const int row = t >> 2;
        const int kc  = (t & 3) * 8;
        const unsigned short* gA0 = A + (size_t)(m0 + row) * 1024 + kc;
        const unsigned short* gA1 = gA0 + (size_t)64 * 1024;
        unsigned short* sA0 = &As[row * LDT + kc];
        unsigned short* sA1 = sA0 + 64 * LDT;
        const unsigned short* gB0 = B + (size_t)(n0 + row) * 1024 + kc;
        const unsigned short* gB1 = gB0 + (size_t)64 * 1024;
        unsigned short* sB0 = &Bs[row * LDT + kc];
        unsigned short* sB1 = sB0 + 64 * LDT;
        int4 ra0 = *(const int4*)gA0;
        int4 ra1 = *(const int4*)gA1;
        int4 rb0 = *(const int4*)gB0;
        int4 rb1 = *(const int4*)gB1;
        const int lane = t & 63, wid = t >> 6;
        const int wm = (wid & 1) * 64, wn = (wid >> 1) * 64;
        const unsigned short* pa = &As[(wm + (lane & 15)) * LDT + (lane >> 4) * 8];
        const unsigned short* pb = &Bs[(wn + (lane & 15)) * LDT + (lane >> 4) * 8];
        for (int k0 = 0; k0 < 1024; k0 += 32) {
            *(int4*)sA0 = ra0; *(int4*)sA1 = ra1;
            *(int4*)sB0 = rb0; *(int4*)sB1 = rb1;
            __syncthreads();
            if (k0 + 32 < 1024) {
                ra0 = *(const int4*)(gA0 + k0 + 32);
                ra1 = *(const int4*)(gA1 + k0 + 32);
                rb0 = *(const int4*)(gB0 + k0 + 32);
                rb1 = *(const int4*)(gB1 + k0 + 32);
            }
            short8 af[4], bfr[4];
#pragma unroll
            for (int mi = 0; mi < 4; ++mi) af[mi]  = *(const short8*)(pa + mi * 16 * LDT);
#pragma unroll
            for (int ni = 0; ni < 4; ++ni) bfr[ni] = *(const short8*)(pb + ni * 16 * LDT);
#pragma unroll
            for (int mi = 0; mi < 4; ++mi)
#pragma unroll
                for (int ni = 0; ni < 4; ++ni)
                    acc[mi][ni] = __builtin_amdgcn_mfma_f32_16x16x32_bf16(
                        af[mi], bfr[ni], acc[mi][ni], 0, 0, 0);
            __syncthreads();
        }
        const float* bias = tr.bias[z];
        unsigned short* C = tr.C[z];
        const float sc = (z == 0) ? 0.125f : 1.0f;   // fold softmax scale into q
        const int r0 = (lane >> 4) * 4, cc = lane & 15;
#pragma unroll
        for (int mi = 0; mi < 4; ++mi)
#pragma unroll
            for (int ni = 0; ni < 4; ++ni) {
                const int col = n0 + wn + ni * 16 + cc;
                const float bb = bias ? bias[col] : 0.f;
#pragma unroll
                for (int r = 0; r < 4; ++r) {
                    const int rowi = m0 + wm + mi * 16 + r0 + r;
                    C[(size_t)rowi * 1024 + col] = f2bf((acc[mi][ni][r] + bb) * sc);
                }
            }
    } else {
        // ================= pos path =================
        unsigned short* wg_s = (unsigned short*)smem;          // 16*72
        float* bg_s = (float*)(smem + 2304);                   // 16
        float (*mbox)[4] = (float(*)[4])(smem + 2368);         // 1024*4
        if (t < 128) {
            const int gi = t >> 3, c = (t & 7) * 8;
            unsigned short* d = &wg_s[gi * 72 + c];
#pragma unroll
            for (int u = 0; u < 8; ++u) d[u] = f2bf(Wg[gi * 64 + c + u]);
        }
        if (t < 16) bg_s[t] = bg[t];
#pragma unroll
        for (int i = 0; i < 4; ++i) {
            const int m = t + i * 256;
            const float x1 = rois[m * 5 + 1], y1 = rois[m * 5 + 2];
            const float x2 = rois[m * 5 + 3], y2 = rois[m * 5 + 4];
            mbox[m][0] = (x1 + x2) * 0.5f;
            mbox[m][1] = (y1 + y2) * 0.5f;
            mbox[m][2] = x2 - x1 + 1.f;
            mbox[m][3] = y2 - y1 + 1.f;
        }
        const int n = bx - 192;
        const float x1 = rois[n * 5 + 1], y1 = rois[n * 5 + 2];
        const float x2 = rois[n * 5 + 3], y2 = rois[n * 5 + 4];
        const float cxn = (x1 + x2) * 0.5f, cyn = (y1 + y2) * 0.5f;
        const float wn = x2 - x1 + 1.f, hn = y2 - y1 + 1.f;
        const float iwn = 1.f / wn, ihn = 1.f / hn;
        const float lwn = __logf(wn), lhn = __logf(hn);
        __syncthreads();

        const int lane = t & 63, w = t >> 6;
        const int g  = lane & 15;
        const int qw = lane >> 4;
        const float coff = (qw & 1) ? 1.5707963268f : 0.f;   // cos = sin(x+pi/2)
        const int f0 = qw >> 1;
        const short8 bf0 = *(const short8*)&wg_s[g * 72 + qw * 8];
        const short8 bf1 = *(const short8*)&wg_s[g * 72 + qw * 8 + 32];
        const float bgv = bg_s[g];
        const float invd[8] = {1.f, 0.42169650342f, 0.1778279410f, 0.07498942093f,
                               0.0316227766f, 0.01333521432f, 0.005623413252f, 0.002371373706f};
        unsigned short* outp = logw + (size_t)n * 16384;

        for (int c = w * 16; c < w * 16 + 16; ++c) {
            const int ma = c * 16 + (lane & 15);
            float4 mb = *(const float4*)&mbox[ma][0];
            float p0 = (f0 == 0)
                     ? __logf(fmaxf(fabsf((cxn - mb.x) * iwn), 1e-3f))
                     : __logf(fmaxf(fabsf((cyn - mb.y) * ihn), 1e-3f));
            float p1 = (f0 == 0) ? (lwn - __logf(mb.z)) : (lhn - __logf(mb.w));
            p0 *= 100.f; p1 *= 100.f;
            short8 af0, af1;
#pragma unroll
            for (int rr = 0; rr < 8; ++rr) {
                af0[rr] = (short)f2bf(__sinf(p0 * invd[rr] + coff));
                af1[rr] = (short)f2bf(__sinf(p1 * invd[rr] + coff));
            }
            f32x4 acc = {0.f, 0.f, 0.f, 0.f};
            acc = __builtin_amdgcn_mfma_f32_16x16x32_bf16(af0, bf0, acc, 0, 0, 0);
            acc = __builtin_amdgcn_mfma_f32_16x16x32_bf16(af1, bf1, acc, 0, 0, 0);
            unsigned short o[4];
#pragma unroll
            for (int r = 0; r < 4; ++r)
                o[r] = f2bf(__logf(fmaxf(acc[r] + bgv, 1e-6f)));
            const unsigned lo = (unsigned)o[0] | ((unsigned)o[1] << 16);
            const unsigned hi = (unsigned)o[2] | ((unsigned)o[3] << 16);
            *(uint2*)&outp[(size_t)g * 1024 + c * 16 + qw * 4] = make_uint2(lo, hi);
        }
    }
}

// ---------------------------------------------------------------------------
// Fused aff + logw + softmax + rel, FLASH style.
// Block = (16-row n-tile, g), 4 waves; wave w owns m in [w*256,(w+1)*256).
// logw tile (16 x 1024, 32KB) is DMA-staged into LDS via global_load_lds
// with an XOR swizzle applied on the GLOBAL source address (linear LDS dest),
// so row-strided ds_read_b64 is ~2-way (free) instead of 16-way conflicted.
// Ored is unioned over the logw region (dead after the main loop).
// ---------------------------------------------------------------------------
#define PPAD 88

__global__ __launch_bounds__(256) void attn_kernel(
    const unsigned short* __restrict__ qb, const unsigned short* __restrict__ kb,
    const unsigned short* __restrict__ logw, const unsigned short* __restrict__ FWt,
    const float* __restrict__ bv, float* __restrict__ out)
{
    __shared__ __align__(16) char smem[46848];
    char* lws = smem;                                         // 32KB logw / later Ored
    unsigned short* qs   = (unsigned short*)(smem + 32768);   // 16*72
    unsigned short* Pbuf = (unsigned short*)(smem + 32768 + 2304);  // 4*16*PPAD
    float* mw_s = (float*)(smem + 32768 + 2304 + 11264);      // [4][16]
    float* sw_s = mw_s + 64;

    const int t  = threadIdx.x;
    const int n0 = blockIdx.x * 16;
    const int g  = blockIdx.y;
    const int lane = t & 63, w = t >> 6;
    const int qw = lane >> 4, lx = lane & 15;

    // ---- async DMA stage of logw tile; 32 chunks of 1KB; wave w -> chunks w*8.. ----
#pragma unroll
    for (int j = 0; j < 8; ++j) {
        const int c   = w * 8 + j;
        const int row = c >> 1;
        const unsigned mbyte = ((unsigned)((c & 1) << 10) + (unsigned)lane * 16u)
                             ^ (((unsigned)row & 7u) << 4);
        const unsigned short* gp =
            logw + (size_t)(n0 + row) * 16384 + g * 1024 + (mbyte >> 1);
        __builtin_amdgcn_global_load_lds(
            (const __attribute__((address_space(1))) void*)gp,
            (__attribute__((address_space(3))) void*)(lws + c * 1024), 16, 0, 0);
    }
    if (t < 128) {
        const int row = t >> 3, c = (t & 7) * 8;
        *(int4*)&qs[row * 72 + c] =
            *(const int4*)&qb[(size_t)(n0 + row) * 1024 + g * 64 + c];
    }
    __syncthreads();   // drains vmcnt: all logw chunks + q staged

    const short8 bq0 = *(const short8*)&qs[lx * 72 + qw * 8];
    const short8 bq1 = *(const short8*)&qs[lx * 72 + qw * 8 + 32];
    unsigned short* Pw = Pbuf + w * 16 * PPAD;

    f32x4 acc[4];
    const f32x4 z4 = {0.f, 0.f, 0.f, 0.f};
#pragma unroll
    for (int nb = 0; nb < 4; ++nb) acc[nb] = z4;
    float mrow = -1e30f, srow = 0.f;

    const unsigned short* kbase = kb + g * 64 + qw * 8;                        // + m*1024
    const unsigned short* fbase = FWt + (size_t)(g * 64 + lx) * 1024 + qw * 8; // + nb*16384 + moff
    const unsigned swz = ((unsigned)lx & 7u) << 4;
    const char* lrow = lws + lx * 2048;

    short8 kf[2][4][2];
#pragma unroll
    for (int tt = 0; tt < 4; ++tt) {
        const unsigned short* kp = kbase + (size_t)(w * 256 + tt * 16 + lx) * 1024;
        kf[0][tt][0] = *(const short8*)kp;
        kf[0][tt][1] = *(const short8*)(kp + 32);
    }

#pragma unroll
    for (int it = 0; it < 4; ++it) {
        const int m0  = w * 256 + it * 64;
        const int cur = it & 1, nxt = cur ^ 1;

        // ---- prefetch next iteration's K frags ----
        if (it < 3) {
#pragma unroll
            for (int tt = 0; tt < 4; ++tt) {
                const unsigned short* kp = kbase + (size_t)(m0 + 64 + tt * 16 + lx) * 1024;
                kf[nxt][tt][0] = *(const short8*)kp;
                kf[nxt][tt][1] = *(const short8*)(kp + 32);
            }
        }

        // ---- S = mfma(K, Q): D[m][n], lane holds n=lx, m=tt*16+qw*4+r ----
        f32x4 s[4];
#pragma unroll
        for (int tt = 0; tt < 4; ++tt) {
            f32x4 z = z4;
            z = __builtin_amdgcn_mfma_f32_16x16x32_bf16(kf[cur][tt][0], bq0, z, 0, 0, 0);
            s[tt] = __builtin_amdgcn_mfma_f32_16x16x32_bf16(kf[cur][tt][1], bq1, z, 0, 0, 0);
        }

        // ---- FW frags for PV (L2-resident) ----
        short8 fw[2][4];
#pragma unroll
        for (int ks = 0; ks < 2; ++ks)
#pragma unroll
            for (int nb = 0; nb < 4; ++nb)
                fw[ks][nb] = *(const short8*)(fbase + (size_t)nb * 16384 + m0 + ks * 32);

        // ---- v = S + logw (from swizzled LDS); chunk max ----
        float v[4][4];
        float cmx = -1e30f;
#pragma unroll
        for (int tt = 0; tt < 4; ++tt) {
            const unsigned mby = (unsigned)(w * 512 + it * 128 + tt * 32 + qw * 8);
            const uint2 lw = *(const uint2*)(lrow + (mby ^ swz));
            v[tt][0] = s[tt][0] + bf2f((unsigned short)(lw.x & 0xffff));
            v[tt][1] = s[tt][1] + bf2f((unsigned short)(lw.x >> 16));
            v[tt][2] = s[tt][2] + bf2f((unsigned short)(lw.y & 0xffff));
            v[tt][3] = s[tt][3] + bf2f((unsigned short)(lw.y >> 16));
            cmx = fmaxf(cmx, fmaxf(fmaxf(v[tt][0], v[tt][1]), fmaxf(v[tt][2], v[tt][3])));
        }
        cmx = fmaxf(cmx, __shfl_xor(cmx, 16));
        cmx = fmaxf(cmx, __shfl_xor(cmx, 32));

        // ---- online rescale (per-lane f: acc rows are n=lx) ----
        const float nm = fmaxf(mrow, cmx);
        const float f  = __expf(mrow - nm);
        mrow = nm;
        srow *= f;
#pragma unroll
        for (int nb = 0; nb < 4; ++nb) {
            acc[nb][0] *= f; acc[nb][1] *= f;
            acc[nb][2] *= f; acc[nb][3] *= f;
        }

        // ---- P = exp(v - m) -> packed 8B LDS writes ----
#pragma unroll
        for (int tt = 0; tt < 4; ++tt) {
            const float p0 = __expf(v[tt][0] - nm);
            const float p1 = __expf(v[tt][1] - nm);
            const float p2 = __expf(v[tt][2] - nm);
            const float p3 = __expf(v[tt][3] - nm);
            srow += (p0 + p1) + (p2 + p3);
            uint2 pk;
            pk.x = (unsigned)f2bf(p0) | ((unsigned)f2bf(p1) << 16);
            pk.y = (unsigned)f2bf(p2) | ((unsigned)f2bf(p3) << 16);
            *(uint2*)&Pw[lx * PPAD + tt * 16 + qw * 4] = pk;
        }

        // ---- PV = mfma(FW, P): D[d][n] ----
#pragma unroll
        for (int ks = 0; ks < 2; ++ks) {
            const short8 ap = *(const short8*)&Pw[lx * PPAD + ks * 32 + qw * 8];
#pragma unroll
            for (int nb = 0; nb < 4; ++nb)
                acc[nb] = __builtin_amdgcn_mfma_f32_16x16x32_bf16(fw[ks][nb], ap, acc[nb], 0, 0, 0);
        }
    }

    // ---- all waves done with lws -> safe to reuse as Ored ----
    __syncthreads();
    srow += __shfl_xor(srow, 16);
    srow += __shfl_xor(srow, 32);
    float* Ored = (float*)smem;              // [4][16][68]
#pragma unroll
    for (int nb = 0; nb < 4; ++nb)
#pragma unroll
        for (int r = 0; r < 4; ++r)
            Ored[(w * 16 + lx) * 68 + nb * 16 + qw * 4 + r] = acc[nb][r];
    if (lane < 16) {
        mw_s[w * 16 + lx] = mrow;
        sw_s[w * 16 + lx] = srow;
    }
    __syncthreads();

    // ---- cross-wave combine ----
    {
        const int nn = t >> 4, d0 = (t & 15) * 4;
        const float m0w = mw_s[nn],      m1w = mw_s[16 + nn];
        const float m2w = mw_s[32 + nn], m3w = mw_s[48 + nn];
        const float M = fmaxf(fmaxf(m0w, m1w), fmaxf(m2w, m3w));
        const float f0w = __expf(m0w - M), f1w = __expf(m1w - M);
        const float f2w = __expf(m2w - M), f3w = __expf(m3w - M);
        const float stot = sw_s[nn] * f0w + sw_s[16 + nn] * f1w
                         + sw_s[32 + nn] * f2w + sw_s[48 + nn] * f3w;
        float4 o0 = *(const float4*)&Ored[(0  + nn) * 68 + d0];
        float4 o1 = *(const float4*)&Ored[(16 + nn) * 68 + d0];
        float4 o2 = *(const float4*)&Ored[(32 + nn) * 68 + d0];
        float4 o3 = *(const float4*)&Ored[(48 + nn) * 68 + d0];
        const float inv = 1.f / stot;
        float4 b4 = *(const float4*)&bv[g * 64 + d0];
        float4 o;
        o.x = (o0.x * f0w + o1.x * f1w + o2.x * f2w + o3.x * f3w) * inv + b4.x;
        o.y = (o0.y * f0w + o1.y * f1w + o2.y * f2w + o3.y * f3w) * inv + b4.y;
        o.z = (o0.z * f0w + o1.z * f1w + o2.z * f2w + o3.z * f3w) * inv + b4.z;
        o.w = (o0.w * f0w + o1.w * f1w + o2.w * f2w + o3.w * f3w) * inv + b4.w;
        *(float4*)&out[(size_t)(n0 + nn) * 1024 + g * 64 + d0] = o;
    }
}

extern "C" void kernel_launch(void* const* d_in, const int* in_sizes, int n_in,
                              void* d_out, int out_size, void* d_ws, size_t ws_size,
                              hipStream_t stream)
{
    const float* feats = (const float*)d_in[0];
    const float* rois  = (const float*)d_in[1];
    const float* Wq    = (const float*)d_in[2];
    const float* bq    = (const float*)d_in[3];
    const float* Wk    = (const float*)d_in[4];
    const float* bk    = (const float*)d_in[5];
    const float* Wg    = (const float*)d_in[6];
    const float* bg    = (const float*)d_in[7];
    const float* Wv    = (const float*)d_in[8];
    const float* bv    = (const float*)d_in[9];
    float* out = (float*)d_out;

    char* wsb = (char*)d_ws;
    unsigned short* logwb  = (unsigned short*)(wsb + (0ull  << 20));  // 32MB
    unsigned short* featsb = (unsigned short*)(wsb + (64ull << 20));  // 2MB
    unsigned short* qb     = (unsigned short*)(wsb + (66ull << 20));
    unsigned short* kb     = (unsigned short*)(wsb + (68ull << 20));
    unsigned short* FWtb   = (unsigned short*)(wsb + (70ull << 20));
    unsigned short* Wqb    = (unsigned short*)(wsb + (80ull << 20));  // out of logw range
    unsigned short* Wkb    = (unsigned short*)(wsb + (82ull << 20));
    unsigned short* Wvb    = (unsigned short*)(wsb + (84ull << 20));

    cvt_kernel<<<dim3(512, 4), 256, 0, stream>>>(feats, Wq, Wk, Wv,
                                                 featsb, Wqb, Wkb, Wvb);

    Triples tr;
    tr.A[0] = featsb; tr.B[0] = Wqb;    tr.C[0] = qb;   tr.bias[0] = bq;
    tr.A[1] = featsb; tr.B[1] = Wkb;    tr.C[1] = kb;   tr.bias[1] = bk;
    tr.A[2] = Wvb;    tr.B[2] = featsb; tr.C[2] = FWtb; tr.bias[2] = nullptr;
    // 192 GEMM blocks + 1024 pos blocks in one dispatch (overlap)
    prep_kernel<<<1216, 256, 0, stream>>>(tr, rois, Wg, bg, logwb);

    attn_kernel<<<dim3(64, 16), 256, 0, stream>>>(qb, kb, logwb, FWtb, bv, out);
}

// Round 7
// 67.876 us; speedup vs baseline: 4.9645x; 1.1794x over previous
//
#include <hip/hip_runtime.h>
#include <math.h>

#define N_ROIS 1024
#define C_DIM  1024

typedef __attribute__((ext_vector_type(8))) short short8;
typedef __attribute__((ext_vector_type(4))) float f32x4;

__device__ __forceinline__ unsigned short f2bf(float x) {
    union { float f; unsigned u; } v; v.f = x;
    unsigned r = v.u + 0x7fffu + ((v.u >> 16) & 1u);
    return (unsigned short)(r >> 16);
}
__device__ __forceinline__ float bf2f(unsigned short u) {
    return __uint_as_float((unsigned)u << 16);
}

// ---------------------------------------------------------------------------
// Bulk f32 -> bf16 convert of 4 tensors (1M elems each).
// ---------------------------------------------------------------------------
__global__ __launch_bounds__(256) void cvt_kernel(
    const float* __restrict__ s0, const float* __restrict__ s1,
    const float* __restrict__ s2, const float* __restrict__ s3,
    unsigned short* __restrict__ d0, unsigned short* __restrict__ d1,
    unsigned short* __restrict__ d2, unsigned short* __restrict__ d3)
{
    const float* s; unsigned short* d;
    switch (blockIdx.y) {
        case 0:  s = s0; d = d0; break;
        case 1:  s = s1; d = d1; break;
        case 2:  s = s2; d = d2; break;
        default: s = s3; d = d3; break;
    }
    const int i = (blockIdx.x * 256 + threadIdx.x) * 8;
    float4 a = *(const float4*)&s[i];
    float4 b = *(const float4*)&s[i + 4];
    short8 o;
    o[0] = (short)f2bf(a.x); o[1] = (short)f2bf(a.y);
    o[2] = (short)f2bf(a.z); o[3] = (short)f2bf(a.w);
    o[4] = (short)f2bf(b.x); o[5] = (short)f2bf(b.y);
    o[6] = (short)f2bf(b.z); o[7] = (short)f2bf(b.w);
    *(short8*)&d[i] = o;
}

struct Triples {
    const unsigned short* A[3];
    const unsigned short* B[3];
    unsigned short*       C[3];
    const float*          bias[3];
};

// ---------------------------------------------------------------------------
// prep_kernel: flat grid. Blocks [0,192): three 1024^3 NT GEMMs (q x0.125, k,
// FWt). Blocks [192,1216): pos -> logw with LDS-transposed, coalesced writes.
// ---------------------------------------------------------------------------
__global__ __launch_bounds__(256) void prep_kernel(
    Triples tr, const float* __restrict__ rois, const float* __restrict__ Wg,
    const float* __restrict__ bg, unsigned short* __restrict__ logw)
{
    __shared__ __align__(16) char smem[52224];
    const int bx = blockIdx.x;
    const int t  = threadIdx.x;

    if (bx < 192) {
        // ================= GEMM path =================
        constexpr int LDT = 40;
        unsigned short* As = (unsigned short*)smem;       // 128*40
        unsigned short* Bs = As + 128 * LDT;              // 128*40
        const int z   = bx >> 6;
        const int rem = bx & 63;
        const int m0 = (rem >> 3) * 128, n0 = (rem & 7) * 128;
        const unsigned short* A = tr.A[z];
        const unsigned short* B = tr.B[z];
        f32x4 acc[4][4];
        const f32x4 z4 = {0.f, 0.f, 0.f, 0.f};
#pragma unroll
        for (int i = 0; i < 4; ++i)
#pragma unroll
            for (int j = 0; j < 4; ++j) acc[i][j] = z4;

        const int row = t >> 2;
        const int kc  = (t & 3) * 8;
        const unsigned short* gA0 = A + (size_t)(m0 + row) * 1024 + kc;
        const unsigned short* gA1 = gA0 + (size_t)64 * 1024;
        unsigned short* sA0 = &As[row * LDT + kc];
        unsigned short* sA1 = sA0 + 64 * LDT;
        const unsigned short* gB0 = B + (size_t)(n0 + row) * 1024 + kc;
        const unsigned short* gB1 = gB0 + (size_t)64 * 1024;
        unsigned short* sB0 = &Bs[row * LDT + kc];
        unsigned short* sB1 = sB0 + 64 * LDT;
        int4 ra0 = *(const int4*)gA0;
        int4 ra1 = *(const int4*)gA1;
        int4 rb0 = *(const int4*)gB0;
        int4 rb1 = *(const int4*)gB1;
        const int lane = t & 63, wid = t >> 6;
        const int wm = (wid & 1) * 64, wn = (wid >> 1) * 64;
        const unsigned short* pa = &As[(wm + (lane & 15)) * LDT + (lane >> 4) * 8];
        const unsigned short* pb = &Bs[(wn + (lane & 15)) * LDT + (lane >> 4) * 8];
        for (int k0 = 0; k0 < 1024; k0 += 32) {
            *(int4*)sA0 = ra0; *(int4*)sA1 = ra1;
            *(int4*)sB0 = rb0; *(int4*)sB1 = rb1;
            __syncthreads();
            if (k0 + 32 < 1024) {
                ra0 = *(const int4*)(gA0 + k0 + 32);
                ra1 = *(const int4*)(gA1 + k0 + 32);
                rb0 = *(const int4*)(gB0 + k0 + 32);
                rb1 = *(const int4*)(gB1 + k0 + 32);
            }
            short8 af[4], bfr[4];
#pragma unroll
            for (int mi = 0; mi < 4; ++mi) af[mi]  = *(const short8*)(pa + mi * 16 * LDT);
#pragma unroll
            for (int ni = 0; ni < 4; ++ni) bfr[ni] = *(const short8*)(pb + ni * 16 * LDT);
#pragma unroll
            for (int mi = 0; mi < 4; ++mi)
#pragma unroll
                for (int ni = 0; ni < 4; ++ni)
                    acc[mi][ni] = __builtin_amdgcn_mfma_f32_16x16x32_bf16(
                        af[mi], bfr[ni], acc[mi][ni], 0, 0, 0);
            __syncthreads();
        }
        const float* bias = tr.bias[z];
        unsigned short* C = tr.C[z];
        const float sc = (z == 0) ? 0.125f : 1.0f;
        const int r0 = (lane >> 4) * 4, cc = lane & 15;
#pragma unroll
        for (int mi = 0; mi < 4; ++mi)
#pragma unroll
            for (int ni = 0; ni < 4; ++ni) {
                const int col = n0 + wn + ni * 16 + cc;
                const float bb = bias ? bias[col] : 0.f;
#pragma unroll
                for (int r = 0; r < 4; ++r) {
                    const int rowi = m0 + wm + mi * 16 + r0 + r;
                    C[(size_t)rowi * 1024 + col] = f2bf((acc[mi][ni][r] + bb) * sc);
                }
            }
    } else {
        // ================= pos path =================
        unsigned short* wg_s = (unsigned short*)smem;          // 16*72
        float* bg_s = (float*)(smem + 2304);                   // 16
        float (*mbox)[4] = (float(*)[4])(smem + 2368);         // 1024*4 f32
        const int w = t >> 6, lane = t & 63;
        unsigned short* ptile = (unsigned short*)(smem + 18752) + w * 4160; // [16 g][260]
        if (t < 128) {
            const int gi = t >> 3, c = (t & 7) * 8;
            unsigned short* d = &wg_s[gi * 72 + c];
#pragma unroll
            for (int u = 0; u < 8; ++u) d[u] = f2bf(Wg[gi * 64 + c + u]);
        }
        if (t < 16) bg_s[t] = bg[t];
#pragma unroll
        for (int i = 0; i < 4; ++i) {
            const int m = t + i * 256;
            const float x1 = rois[m * 5 + 1], y1 = rois[m * 5 + 2];
            const float x2 = rois[m * 5 + 3], y2 = rois[m * 5 + 4];
            mbox[m][0] = (x1 + x2) * 0.5f;
            mbox[m][1] = (y1 + y2) * 0.5f;
            mbox[m][2] = x2 - x1 + 1.f;
            mbox[m][3] = y2 - y1 + 1.f;
        }
        const int n = bx - 192;
        const float x1 = rois[n * 5 + 1], y1 = rois[n * 5 + 2];
        const float x2 = rois[n * 5 + 3], y2 = rois[n * 5 + 4];
        const float cxn = (x1 + x2) * 0.5f, cyn = (y1 + y2) * 0.5f;
        const float wn = x2 - x1 + 1.f, hn = y2 - y1 + 1.f;
        const float iwn = 1.f / wn, ihn = 1.f / hn;
        const float lwn = __logf(wn), lhn = __logf(hn);
        __syncthreads();

        const int g  = lane & 15;
        const int qw = lane >> 4;
        const float coff = (qw & 1) ? 1.5707963268f : 0.f;   // cos = sin(x+pi/2)
        const int f0 = qw >> 1;
        const short8 bf0 = *(const short8*)&wg_s[g * 72 + qw * 8];
        const short8 bf1 = *(const short8*)&wg_s[g * 72 + qw * 8 + 32];
        const float bgv = bg_s[g];
        const float invd[8] = {1.f, 0.42169650342f, 0.1778279410f, 0.07498942093f,
                               0.0316227766f, 0.01333521432f, 0.005623413252f, 0.002371373706f};

        for (int cl = 0; cl < 16; ++cl) {
            const int c  = w * 16 + cl;
            const int ma = c * 16 + g;
            float4 mb = *(const float4*)&mbox[ma][0];
            float p0 = (f0 == 0)
                     ? __logf(fmaxf(fabsf((cxn - mb.x) * iwn), 1e-3f))
                     : __logf(fmaxf(fabsf((cyn - mb.y) * ihn), 1e-3f));
            float p1 = (f0 == 0) ? (lwn - __logf(mb.z)) : (lhn - __logf(mb.w));
            p0 *= 100.f; p1 *= 100.f;
            short8 af0, af1;
#pragma unroll
            for (int rr = 0; rr < 8; ++rr) {
                af0[rr] = (short)f2bf(__sinf(p0 * invd[rr] + coff));
                af1[rr] = (short)f2bf(__sinf(p1 * invd[rr] + coff));
            }
            f32x4 acc = {0.f, 0.f, 0.f, 0.f};
            acc = __builtin_amdgcn_mfma_f32_16x16x32_bf16(af0, bf0, acc, 0, 0, 0);
            acc = __builtin_amdgcn_mfma_f32_16x16x32_bf16(af1, bf1, acc, 0, 0, 0);
            // lane holds C[m'=qw*4+r][g=lane&15] -> stash into per-wave LDS tile
            unsigned short o[4];
#pragma unroll
            for (int r = 0; r < 4; ++r)
                o[r] = f2bf(__logf(fmaxf(acc[r] + bgv, 1e-6f)));
            uint2 pk;
            pk.x = (unsigned)o[0] | ((unsigned)o[1] << 16);
            pk.y = (unsigned)o[2] | ((unsigned)o[3] << 16);
            *(uint2*)&ptile[g * 260 + cl * 16 + qw * 4] = pk;
        }
        // coalesced store: per g-row 512B contiguous (wave-synchronous LDS)
        unsigned short* outp = logw + (size_t)n * 16384 + w * 256;
#pragma unroll
        for (int gg = 0; gg < 16; ++gg) {
            const uint2 pv = *(const uint2*)&ptile[gg * 260 + lane * 4];
            *(uint2*)&outp[gg * 1024 + lane * 4] = pv;
        }
    }
}

// ---------------------------------------------------------------------------
// attn v7: block = (g, 64-n tile) = 256 blocks, 4 waves; wave W owns n rows
// W*16..W*16+15 for the FULL m sweep (no cross-wave combine). Per 64-m chunk:
// K/FW/logw tiles DMA-staged into double-buffered LDS (global_load_lds,
// source-side XOR swizzle; swizzled ds_read on consume). Flash online softmax
// per wave. One barrier per chunk; DMA for chunk i+1 in flight across
// compute of chunk i.
// LDS map: q[0,8K) K[8K,24K) FW[24K,40K) logw[40K,56K) P[56K,65K)
// ---------------------------------------------------------------------------
#define QOFF 0
#define KOFF 8192
#define FOFF 24576
#define LOFF 40960
#define POFF 57344
#define PPAD 72

__global__ __launch_bounds__(256) void attn_kernel(
    const unsigned short* __restrict__ qb, const unsigned short* __restrict__ kb,
    const unsigned short* __restrict__ logw, const unsigned short* __restrict__ FWt,
    const float* __restrict__ bv, float* __restrict__ out)
{
    __shared__ __align__(16) char smem[66560];

    const int t = threadIdx.x;
    const int bid = blockIdx.x;
    // XCD-aware mapping: g pair per XCD so kb/FWt g-slices stay L2-local
    const int g  = (bid & 7) * 2 + ((bid >> 3) >> 4);
    const int n0 = ((bid >> 3) & 15) * 64;

    const int lane = t & 63, W = t >> 6;
    const int qw = lane >> 4, lx = lane & 15;
    const int lx7 = lx & 7;
    const int r8 = lane >> 3, u = lane & 7;

#define GLD(srcp, ldsoff) __builtin_amdgcn_global_load_lds( \
        (const __attribute__((address_space(1))) void*)(srcp), \
        (__attribute__((address_space(3))) void*)(smem + (ldsoff)), 16, 0, 0)

    // ---- prologue: stage q tile + chunk 0 ----
#pragma unroll
    for (int j = 0; j < 2; ++j) {
        const int c = W * 2 + j;
        const int r = c * 8 + r8;
        GLD(qb + (size_t)(n0 + r) * 1024 + g * 64 + ((u ^ (r & 7)) * 8),
            QOFF + c * 1024);
        GLD(kb + (size_t)r * 1024 + g * 64 + ((u ^ (r & 7)) * 8),
            KOFF + c * 1024);
        GLD(FWt + (size_t)(g * 64 + r) * 1024 + ((u ^ (r & 7)) * 8),
            FOFF + c * 1024);
        GLD(logw + (size_t)(n0 + r) * 16384 + g * 1024 + (((2 * u) ^ (r & 6)) * 4),
            LOFF + c * 1024);
    }
    __syncthreads();

    const unsigned short* qS = (const unsigned short*)(smem + QOFF);
    const int qrow = W * 16 + lx;
    const short8 bq0 = *(const short8*)(qS + qrow * 64 + ((qw ^ lx7) * 8));
    const short8 bq1 = *(const short8*)(qS + qrow * 64 + (((qw + 4) ^ lx7) * 8));
    unsigned short* Pw = (unsigned short*)(smem + POFF) + W * 16 * PPAD;

    f32x4 acc[4];
    const f32x4 z4 = {0.f, 0.f, 0.f, 0.f};
#pragma unroll
    for (int nb = 0; nb < 4; ++nb) acc[nb] = z4;
    float mrow = -1e30f, srow = 0.f;

    for (int i = 0; i < 16; ++i) {
        const int cur = i & 1;
        // ---- issue DMA for chunk i+1 into the other buffer ----
        if (i < 15) {
            const int mc = (i + 1) * 64;
            const int nxt = cur ^ 1;
#pragma unroll
            for (int j = 0; j < 2; ++j) {
                const int c = W * 2 + j;
                const int r = c * 8 + r8;
                GLD(kb + (size_t)(mc + r) * 1024 + g * 64 + ((u ^ (r & 7)) * 8),
                    KOFF + nxt * 8192 + c * 1024);
                GLD(FWt + (size_t)(g * 64 + r) * 1024 + mc + ((u ^ (r & 7)) * 8),
                    FOFF + nxt * 8192 + c * 1024);
                GLD(logw + (size_t)(n0 + r) * 16384 + g * 1024 + mc
                        + (((2 * u) ^ (r & 6)) * 4),
                    LOFF + nxt * 8192 + c * 1024);
            }
        }

        const unsigned short* Kc = (const unsigned short*)(smem + KOFF + cur * 8192);
        const unsigned short* Fc = (const unsigned short*)(smem + FOFF + cur * 8192);
        const unsigned short* Lc = (const unsigned short*)(smem + LOFF + cur * 8192);

        // ---- S = mfma(K, Q): D[m][n], lane holds n=lx, m=tt*16+qw*4+r ----
        f32x4 s[4];
#pragma unroll
        for (int tt = 0; tt < 4; ++tt) {
            const unsigned short* kr = Kc + (tt * 16 + lx) * 64;
            short8 a0 = *(const short8*)(kr + ((qw ^ lx7) * 8));
            short8 a1 = *(const short8*)(kr + (((qw + 4) ^ lx7) * 8));
            f32x4 z = z4;
            z = __builtin_amdgcn_mfma_f32_16x16x32_bf16(a0, bq0, z, 0, 0, 0);
            s[tt] = __builtin_amdgcn_mfma_f32_16x16x32_bf16(a1, bq1, z, 0, 0, 0);
        }

        // ---- v = S + logw (swizzled LDS read); chunk max ----
        const unsigned short* Lr = Lc + (W * 16 + lx) * 64;
        float v[4][4];
        float cmx = -1e30f;
#pragma unroll
        for (int tt = 0; tt < 4; ++tt) {
            const int off = ((tt * 32 + qw * 8) ^ ((lx & 6) << 3)) >> 1;
            const uint2 lw = *(const uint2*)(Lr + off);
            v[tt][0] = s[tt][0] + bf2f((unsigned short)(lw.x & 0xffff));
            v[tt][1] = s[tt][1] + bf2f((unsigned short)(lw.x >> 16));
            v[tt][2] = s[tt][2] + bf2f((unsigned short)(lw.y & 0xffff));
            v[tt][3] = s[tt][3] + bf2f((unsigned short)(lw.y >> 16));
            cmx = fmaxf(cmx, fmaxf(fmaxf(v[tt][0], v[tt][1]), fmaxf(v[tt][2], v[tt][3])));
        }
        cmx = fmaxf(cmx, __shfl_xor(cmx, 16));
        cmx = fmaxf(cmx, __shfl_xor(cmx, 32));

        // ---- online rescale ----
        const float nm = fmaxf(mrow, cmx);
        const float f  = __expf(mrow - nm);
        mrow = nm;
        srow *= f;
#pragma unroll
        for (int nb = 0; nb < 4; ++nb) {
            acc[nb][0] *= f; acc[nb][1] *= f;
            acc[nb][2] *= f; acc[nb][3] *= f;
        }

        // ---- P = exp(v - m) -> packed LDS (wave-private) ----
#pragma unroll
        for (int tt = 0; tt < 4; ++tt) {
            const float p0 = __expf(v[tt][0] - nm);
            const float p1 = __expf(v[tt][1] - nm);
            const float p2 = __expf(v[tt][2] - nm);
            const float p3 = __expf(v[tt][3] - nm);
            srow += (p0 + p1) + (p2 + p3);
            uint2 pk;
            pk.x = (unsigned)f2bf(p0) | ((unsigned)f2bf(p1) << 16);
            pk.y = (unsigned)f2bf(p2) | ((unsigned)f2bf(p3) << 16);
            *(uint2*)&Pw[lx * PPAD + tt * 16 + qw * 4] = pk;
        }

        // ---- PV = mfma(FW, P): D[d][n] ----
#pragma unroll
        for (int ks = 0; ks < 2; ++ks) {
            const short8 ap = *(const short8*)&Pw[lx * PPAD + ks * 32 + qw * 8];
#pragma unroll
            for (int nb = 0; nb < 4; ++nb) {
                const unsigned short* fr = Fc + (nb * 16 + lx) * 64;
                short8 fb = *(const short8*)(fr + (((ks * 4 + qw) ^ lx7) * 8));
                acc[nb] = __builtin_amdgcn_mfma_f32_16x16x32_bf16(fb, ap, acc[nb], 0, 0, 0);
            }
        }

        __syncthreads();   // drains DMA for i+1; all waves done with cur
    }

    // ---- epilogue: per-wave normalize, LDS transpose, coalesced store ----
    srow += __shfl_xor(srow, 16);
    srow += __shfl_xor(srow, 32);
    const float inv = 1.f / srow;
    float* Ow = (float*)smem + W * 16 * 68;     // reuse q/K region (all dead)
#pragma unroll
    for (int nb = 0; nb < 4; ++nb)
#pragma unroll
        for (int r = 0; r < 4; ++r)
            Ow[lx * 68 + nb * 16 + qw * 4 + r] = acc[nb][r] * inv;
    // wave-synchronous: same wave reads its own region
    {
        const int row = lane >> 2, d0 = (lane & 3) * 16;
        const float* Orow = (float*)smem + W * 16 * 68 + row * 68;
        float* op = out + (size_t)(n0 + W * 16 + row) * 1024 + g * 64 + d0;
#pragma unroll
        for (int j = 0; j < 4; ++j) {
            float4 o = *(const float4*)(Orow + d0 + j * 4);
            const float4 b4 = *(const float4*)&bv[g * 64 + d0 + j * 4];
            o.x += b4.x; o.y += b4.y; o.z += b4.z; o.w += b4.w;
            *(float4*)(op + j * 4) = o;
        }
    }
#undef GLD
}

extern "C" void kernel_launch(void* const* d_in, const int* in_sizes, int n_in,
                              void* d_out, int out_size, void* d_ws, size_t ws_size,
                              hipStream_t stream)
{
    const float* feats = (const float*)d_in[0];
    const float* rois  = (const float*)d_in[1];
    const float* Wq    = (const float*)d_in[2];
    const float* bq    = (const float*)d_in[3];
    const float* Wk    = (const float*)d_in[4];
    const float* bk    = (const float*)d_in[5];
    const float* Wg    = (const float*)d_in[6];
    const float* bg    = (const float*)d_in[7];
    const float* Wv    = (const float*)d_in[8];
    const float* bv    = (const float*)d_in[9];
    float* out = (float*)d_out;

    char* wsb = (char*)d_ws;
    unsigned short* logwb  = (unsigned short*)(wsb + (0ull  << 20));  // 32MB
    unsigned short* featsb = (unsigned short*)(wsb + (64ull << 20));
    unsigned short* qb     = (unsigned short*)(wsb + (66ull << 20));
    unsigned short* kb     = (unsigned short*)(wsb + (68ull << 20));
    unsigned short* FWtb   = (unsigned short*)(wsb + (70ull << 20));
    unsigned short* Wqb    = (unsigned short*)(wsb + (80ull << 20));
    unsigned short* Wkb    = (unsigned short*)(wsb + (82ull << 20));
    unsigned short* Wvb    = (unsigned short*)(wsb + (84ull << 20));

    cvt_kernel<<<dim3(512, 4), 256, 0, stream>>>(feats, Wq, Wk, Wv,
                                                 featsb, Wqb, Wkb, Wvb);

    Triples tr;
    tr.A[0] = featsb; tr.B[0] = Wqb;    tr.C[0] = qb;   tr.bias[0] = bq;
    tr.A[1] = featsb; tr.B[1] = Wkb;    tr.C[1] = kb;   tr.bias[1] = bk;
    tr.A[2] = Wvb;    tr.B[2] = featsb; tr.C[2] = FWtb; tr.bias[2] = nullptr;
    prep_kernel<<<1216, 256, 0, stream>>>(tr, rois, Wg, bg, logwb);

    attn_kernel<<<256, 256, 0, stream>>>(qb, kb, logwb, FWtb, bv, out);
}

// Round 8
// 64.934 us; speedup vs baseline: 5.1894x; 1.0453x over previous
//
#include <hip/hip_runtime.h>
#include <math.h>

#define N_ROIS 1024
#define C_DIM  1024

typedef __attribute__((ext_vector_type(8))) short short8;
typedef __attribute__((ext_vector_type(4))) float f32x4;

__device__ __forceinline__ unsigned short f2bf(float x) {
    union { float f; unsigned u; } v; v.f = x;
    unsigned r = v.u + 0x7fffu + ((v.u >> 16) & 1u);
    return (unsigned short)(r >> 16);
}
__device__ __forceinline__ float bf2f(unsigned short u) {
    return __uint_as_float((unsigned)u << 16);
}
// HW packed f32x2 -> bf16x2 (RNE), single VALU op on gfx950
__device__ __forceinline__ unsigned cvtpk(float lo, float hi) {
    unsigned r;
    asm("v_cvt_pk_bf16_f32 %0, %1, %2" : "=v"(r) : "v"(lo), "v"(hi));
    return r;
}

// ---------------------------------------------------------------------------
// Bulk f32 -> bf16 convert of 4 tensors (1M elems each).
// ---------------------------------------------------------------------------
__global__ __launch_bounds__(256) void cvt_kernel(
    const float* __restrict__ s0, const float* __restrict__ s1,
    const float* __restrict__ s2, const float* __restrict__ s3,
    unsigned short* __restrict__ d0, unsigned short* __restrict__ d1,
    unsigned short* __restrict__ d2, unsigned short* __restrict__ d3)
{
    const float* s; unsigned short* d;
    switch (blockIdx.y) {
        case 0:  s = s0; d = d0; break;
        case 1:  s = s1; d = d1; break;
        case 2:  s = s2; d = d2; break;
        default: s = s3; d = d3; break;
    }
    const int i = (blockIdx.x * 256 + threadIdx.x) * 8;
    float4 a = *(const float4*)&s[i];
    float4 b = *(const float4*)&s[i + 4];
    uint4 o;
    o.x = cvtpk(a.x, a.y); o.y = cvtpk(a.z, a.w);
    o.z = cvtpk(b.x, b.y); o.w = cvtpk(b.z, b.w);
    *(uint4*)&d[i] = o;
}

struct Triples {
    const unsigned short* A[3];
    const unsigned short* B[3];
    unsigned short*       C[3];
    const float*          bias[3];
};

// ---------------------------------------------------------------------------
// prep_kernel: flat grid. Blocks [0,192): three 1024^3 NT GEMMs (q x0.125, k,
// FWt). Blocks [192,1216): pos -> logw, instruction-dieted (cvt_pk, hoisted
// logs), LDS-transposed coalesced writes.
// ---------------------------------------------------------------------------
__global__ __launch_bounds__(256) void prep_kernel(
    Triples tr, const float* __restrict__ rois, const float* __restrict__ Wg,
    const float* __restrict__ bg, unsigned short* __restrict__ logw)
{
    __shared__ __align__(16) char smem[52224];
    const int bx = blockIdx.x;
    const int t  = threadIdx.x;

    if (bx < 192) {
        // ================= GEMM path =================
        constexpr int LDT = 40;
        unsigned short* As = (unsigned short*)smem;       // 128*40
        unsigned short* Bs = As + 128 * LDT;              // 128*40
        const int z   = bx >> 6;
        const int rem = bx & 63;
        const int m0 = (rem >> 3) * 128, n0 = (rem & 7) * 128;
        const unsigned short* A = tr.A[z];
        const unsigned short* B = tr.B[z];
        f32x4 acc[4][4];
        const f32x4 z4 = {0.f, 0.f, 0.f, 0.f};
#pragma unroll
        for (int i = 0; i < 4; ++i)
#pragma unroll
            for (int j = 0; j < 4; ++j) acc[i][j] = z4;

        const int row = t >> 2;
        const int kc  = (t & 3) * 8;
        const unsigned short* gA0 = A + (size_t)(m0 + row) * 1024 + kc;
        const unsigned short* gA1 = gA0 + (size_t)64 * 1024;
        unsigned short* sA0 = &As[row * LDT + kc];
        unsigned short* sA1 = sA0 + 64 * LDT;
        const unsigned short* gB0 = B + (size_t)(n0 + row) * 1024 + kc;
        const unsigned short* gB1 = gB0 + (size_t)64 * 1024;
        unsigned short* sB0 = &Bs[row * LDT + kc];
        unsigned short* sB1 = sB0 + 64 * LDT;
        int4 ra0 = *(const int4*)gA0;
        int4 ra1 = *(const int4*)gA1;
        int4 rb0 = *(const int4*)gB0;
        int4 rb1 = *(const int4*)gB1;
        const int lane = t & 63, wid = t >> 6;
        const int wm = (wid & 1) * 64, wn = (wid >> 1) * 64;
        const unsigned short* pa = &As[(wm + (lane & 15)) * LDT + (lane >> 4) * 8];
        const unsigned short* pb = &Bs[(wn + (lane & 15)) * LDT + (lane >> 4) * 8];
        for (int k0 = 0; k0 < 1024; k0 += 32) {
            *(int4*)sA0 = ra0; *(int4*)sA1 = ra1;
            *(int4*)sB0 = rb0; *(int4*)sB1 = rb1;
            __syncthreads();
            if (k0 + 32 < 1024) {
                ra0 = *(const int4*)(gA0 + k0 + 32);
                ra1 = *(const int4*)(gA1 + k0 + 32);
                rb0 = *(const int4*)(gB0 + k0 + 32);
                rb1 = *(const int4*)(gB1 + k0 + 32);
            }
            short8 af[4], bfr[4];
#pragma unroll
            for (int mi = 0; mi < 4; ++mi) af[mi]  = *(const short8*)(pa + mi * 16 * LDT);
#pragma unroll
            for (int ni = 0; ni < 4; ++ni) bfr[ni] = *(const short8*)(pb + ni * 16 * LDT);
#pragma unroll
            for (int mi = 0; mi < 4; ++mi)
#pragma unroll
                for (int ni = 0; ni < 4; ++ni)
                    acc[mi][ni] = __builtin_amdgcn_mfma_f32_16x16x32_bf16(
                        af[mi], bfr[ni], acc[mi][ni], 0, 0, 0);
            __syncthreads();
        }
        const float* bias = tr.bias[z];
        unsigned short* C = tr.C[z];
        const float sc = (z == 0) ? 0.125f : 1.0f;
        const int r0 = (lane >> 4) * 4, cc = lane & 15;
#pragma unroll
        for (int mi = 0; mi < 4; ++mi)
#pragma unroll
            for (int ni = 0; ni < 4; ++ni) {
                const int col = n0 + wn + ni * 16 + cc;
                const float bb = bias ? bias[col] : 0.f;
                const int rowi = m0 + wm + mi * 16 + r0;
                const unsigned p01 = cvtpk((acc[mi][ni][0] + bb) * sc,
                                           (acc[mi][ni][1] + bb) * sc);
                const unsigned p23 = cvtpk((acc[mi][ni][2] + bb) * sc,
                                           (acc[mi][ni][3] + bb) * sc);
                C[(size_t)rowi * 1024 + col]       = (unsigned short)(p01 & 0xffff);
                C[(size_t)(rowi + 1) * 1024 + col] = (unsigned short)(p01 >> 16);
                C[(size_t)(rowi + 2) * 1024 + col] = (unsigned short)(p23 & 0xffff);
                C[(size_t)(rowi + 3) * 1024 + col] = (unsigned short)(p23 >> 16);
            }
    } else {
        // ================= pos path =================
        unsigned short* wg_s = (unsigned short*)smem;          // 16*72
        float* bg_s = (float*)(smem + 2304);                   // 16
        float (*mbox)[4] = (float(*)[4])(smem + 2368);         // 1024*4 f32
        const int w = t >> 6, lane = t & 63;
        unsigned short* ptile = (unsigned short*)(smem + 18752) + w * 4160; // [16 g][260]
        if (t < 128) {
            const int gi = t >> 3, c = (t & 7) * 8;
            unsigned short* d = &wg_s[gi * 72 + c];
#pragma unroll
            for (int u = 0; u < 8; ++u) d[u] = f2bf(Wg[gi * 64 + c + u]);
        }
        if (t < 16) bg_s[t] = bg[t];
#pragma unroll
        for (int i = 0; i < 4; ++i) {
            const int m = t + i * 256;
            const float x1 = rois[m * 5 + 1], y1 = rois[m * 5 + 2];
            const float x2 = rois[m * 5 + 3], y2 = rois[m * 5 + 4];
            mbox[m][0] = (x1 + x2) * 0.5f;
            mbox[m][1] = (y1 + y2) * 0.5f;
            mbox[m][2] = __logf(x2 - x1 + 1.f);   // log(w_m), hoisted
            mbox[m][3] = __logf(y2 - y1 + 1.f);   // log(h_m), hoisted
        }
        const int n = bx - 192;
        const float x1 = rois[n * 5 + 1], y1 = rois[n * 5 + 2];
        const float x2 = rois[n * 5 + 3], y2 = rois[n * 5 + 4];
        const float cxn = (x1 + x2) * 0.5f, cyn = (y1 + y2) * 0.5f;
        const float wn = x2 - x1 + 1.f, hn = y2 - y1 + 1.f;
        const float iwn = 1.f / wn, ihn = 1.f / hn;
        const float lwn = __logf(wn), lhn = __logf(hn);
        __syncthreads();

        const int g  = lane & 15;
        const int qw = lane >> 4;
        const float coff = (qw & 1) ? 1.5707963268f : 0.f;   // cos = sin(x+pi/2)
        const int f0 = qw >> 1;
        const short8 bf0 = *(const short8*)&wg_s[g * 72 + qw * 8];
        const short8 bf1 = *(const short8*)&wg_s[g * 72 + qw * 8 + 32];
        const float bgv = bg_s[g];
        const float invd[8] = {1.f, 0.42169650342f, 0.1778279410f, 0.07498942093f,
                               0.0316227766f, 0.01333521432f, 0.005623413252f, 0.002371373706f};

        for (int cl = 0; cl < 16; ++cl) {
            const int c  = w * 16 + cl;
            const int ma = c * 16 + g;
            float4 mb = *(const float4*)&mbox[ma][0];   // cx, cy, lw, lh
            float p0 = (f0 == 0)
                     ? __logf(fmaxf(fabsf((cxn - mb.x) * iwn), 1e-3f))
                     : __logf(fmaxf(fabsf((cyn - mb.y) * ihn), 1e-3f));
            float p1 = (f0 == 0) ? (lwn - mb.z) : (lhn - mb.w);
            p0 *= 100.f; p1 *= 100.f;
            float s0v[8], s1v[8];
#pragma unroll
            for (int rr = 0; rr < 8; ++rr) {
                s0v[rr] = __sinf(p0 * invd[rr] + coff);
                s1v[rr] = __sinf(p1 * invd[rr] + coff);
            }
            union { uint4 u; short8 s; } a0, a1;
            a0.u.x = cvtpk(s0v[0], s0v[1]); a0.u.y = cvtpk(s0v[2], s0v[3]);
            a0.u.z = cvtpk(s0v[4], s0v[5]); a0.u.w = cvtpk(s0v[6], s0v[7]);
            a1.u.x = cvtpk(s1v[0], s1v[1]); a1.u.y = cvtpk(s1v[2], s1v[3]);
            a1.u.z = cvtpk(s1v[4], s1v[5]); a1.u.w = cvtpk(s1v[6], s1v[7]);
            f32x4 acc = {0.f, 0.f, 0.f, 0.f};
            acc = __builtin_amdgcn_mfma_f32_16x16x32_bf16(a0.s, bf0, acc, 0, 0, 0);
            acc = __builtin_amdgcn_mfma_f32_16x16x32_bf16(a1.s, bf1, acc, 0, 0, 0);
            // lane holds C[m'=qw*4+r][g] -> per-wave LDS tile
            const float l0 = __logf(fmaxf(acc[0] + bgv, 1e-6f));
            const float l1 = __logf(fmaxf(acc[1] + bgv, 1e-6f));
            const float l2 = __logf(fmaxf(acc[2] + bgv, 1e-6f));
            const float l3 = __logf(fmaxf(acc[3] + bgv, 1e-6f));
            uint2 pk;
            pk.x = cvtpk(l0, l1);
            pk.y = cvtpk(l2, l3);
            *(uint2*)&ptile[g * 260 + cl * 16 + qw * 4] = pk;
        }
        // coalesced store: per g-row 512B contiguous (wave-synchronous LDS)
        unsigned short* outp = logw + (size_t)n * 16384 + w * 256;
#pragma unroll
        for (int gg = 0; gg < 16; ++gg) {
            const uint2 pv = *(const uint2*)&ptile[gg * 260 + lane * 4];
            *(uint2*)&outp[gg * 1024 + lane * 4] = pv;
        }
    }
}

// ---------------------------------------------------------------------------
// attn: block = (g, 64-n tile) = 256 blocks, 4 waves; wave W owns 16 n rows
// for the FULL m sweep. Per 64-m chunk: K/FW/logw DMA-staged into
// double-buffered LDS (global_load_lds, source-side XOR swizzle), flash
// online softmax per wave, one barrier per chunk.
// LDS map: q[0,8K) K[8K,24K) FW[24K,40K) logw[40K,56K) P[56K,65K)
// ---------------------------------------------------------------------------
#define QOFF 0
#define KOFF 8192
#define FOFF 24576
#define LOFF 40960
#define POFF 57344
#define PPAD 72

__global__ __launch_bounds__(256) void attn_kernel(
    const unsigned short* __restrict__ qb, const unsigned short* __restrict__ kb,
    const unsigned short* __restrict__ logw, const unsigned short* __restrict__ FWt,
    const float* __restrict__ bv, float* __restrict__ out)
{
    __shared__ __align__(16) char smem[66560];

    const int t = threadIdx.x;
    const int bid = blockIdx.x;
    const int g  = (bid & 7) * 2 + ((bid >> 3) >> 4);
    const int n0 = ((bid >> 3) & 15) * 64;

    const int lane = t & 63, W = t >> 6;
    const int qw = lane >> 4, lx = lane & 15;
    const int lx7 = lx & 7;
    const int r8 = lane >> 3, u = lane & 7;

#define GLD(srcp, ldsoff) __builtin_amdgcn_global_load_lds( \
        (const __attribute__((address_space(1))) void*)(srcp), \
        (__attribute__((address_space(3))) void*)(smem + (ldsoff)), 16, 0, 0)

    // ---- prologue: stage q tile + chunk 0 ----
#pragma unroll
    for (int j = 0; j < 2; ++j) {
        const int c = W * 2 + j;
        const int r = c * 8 + r8;
        GLD(qb + (size_t)(n0 + r) * 1024 + g * 64 + ((u ^ (r & 7)) * 8),
            QOFF + c * 1024);
        GLD(kb + (size_t)r * 1024 + g * 64 + ((u ^ (r & 7)) * 8),
            KOFF + c * 1024);
        GLD(FWt + (size_t)(g * 64 + r) * 1024 + ((u ^ (r & 7)) * 8),
            FOFF + c * 1024);
        GLD(logw + (size_t)(n0 + r) * 16384 + g * 1024 + (((2 * u) ^ (r & 6)) * 4),
            LOFF + c * 1024);
    }
    __syncthreads();

    const unsigned short* qS = (const unsigned short*)(smem + QOFF);
    const int qrow = W * 16 + lx;
    const short8 bq0 = *(const short8*)(qS + qrow * 64 + ((qw ^ lx7) * 8));
    const short8 bq1 = *(const short8*)(qS + qrow * 64 + (((qw + 4) ^ lx7) * 8));
    unsigned short* Pw = (unsigned short*)(smem + POFF) + W * 16 * PPAD;

    f32x4 acc[4];
    const f32x4 z4 = {0.f, 0.f, 0.f, 0.f};
#pragma unroll
    for (int nb = 0; nb < 4; ++nb) acc[nb] = z4;
    float mrow = -1e30f, srow = 0.f;

    for (int i = 0; i < 16; ++i) {
        const int cur = i & 1;
        if (i < 15) {
            const int mc = (i + 1) * 64;
            const int nxt = cur ^ 1;
#pragma unroll
            for (int j = 0; j < 2; ++j) {
                const int c = W * 2 + j;
                const int r = c * 8 + r8;
                GLD(kb + (size_t)(mc + r) * 1024 + g * 64 + ((u ^ (r & 7)) * 8),
                    KOFF + nxt * 8192 + c * 1024);
                GLD(FWt + (size_t)(g * 64 + r) * 1024 + mc + ((u ^ (r & 7)) * 8),
                    FOFF + nxt * 8192 + c * 1024);
                GLD(logw + (size_t)(n0 + r) * 16384 + g * 1024 + mc
                        + (((2 * u) ^ (r & 6)) * 4),
                    LOFF + nxt * 8192 + c * 1024);
            }
        }

        const unsigned short* Kc = (const unsigned short*)(smem + KOFF + cur * 8192);
        const unsigned short* Fc = (const unsigned short*)(smem + FOFF + cur * 8192);
        const unsigned short* Lc = (const unsigned short*)(smem + LOFF + cur * 8192);

        // ---- S = mfma(K, Q): D[m][n] ----
        f32x4 s[4];
#pragma unroll
        for (int tt = 0; tt < 4; ++tt) {
            const unsigned short* kr = Kc + (tt * 16 + lx) * 64;
            short8 a0 = *(const short8*)(kr + ((qw ^ lx7) * 8));
            short8 a1 = *(const short8*)(kr + (((qw + 4) ^ lx7) * 8));
            f32x4 z = z4;
            z = __builtin_amdgcn_mfma_f32_16x16x32_bf16(a0, bq0, z, 0, 0, 0);
            s[tt] = __builtin_amdgcn_mfma_f32_16x16x32_bf16(a1, bq1, z, 0, 0, 0);
        }

        // ---- v = S + logw; chunk max ----
        const unsigned short* Lr = Lc + (W * 16 + lx) * 64;
        float v[4][4];
        float cmx = -1e30f;
#pragma unroll
        for (int tt = 0; tt < 4; ++tt) {
            const int off = ((tt * 32 + qw * 8) ^ ((lx & 6) << 3)) >> 1;
            const uint2 lw = *(const uint2*)(Lr + off);
            v[tt][0] = s[tt][0] + bf2f((unsigned short)(lw.x & 0xffff));
            v[tt][1] = s[tt][1] + bf2f((unsigned short)(lw.x >> 16));
            v[tt][2] = s[tt][2] + bf2f((unsigned short)(lw.y & 0xffff));
            v[tt][3] = s[tt][3] + bf2f((unsigned short)(lw.y >> 16));
            cmx = fmaxf(cmx, fmaxf(fmaxf(v[tt][0], v[tt][1]), fmaxf(v[tt][2], v[tt][3])));
        }
        cmx = fmaxf(cmx, __shfl_xor(cmx, 16));
        cmx = fmaxf(cmx, __shfl_xor(cmx, 32));

        // ---- online rescale ----
        const float nm = fmaxf(mrow, cmx);
        const float f  = __expf(mrow - nm);
        mrow = nm;
        srow *= f;
#pragma unroll
        for (int nb = 0; nb < 4; ++nb) {
            acc[nb][0] *= f; acc[nb][1] *= f;
            acc[nb][2] *= f; acc[nb][3] *= f;
        }

        // ---- P = exp(v - m) -> packed LDS (cvt_pk) ----
#pragma unroll
        for (int tt = 0; tt < 4; ++tt) {
            const float p0 = __expf(v[tt][0] - nm);
            const float p1 = __expf(v[tt][1] - nm);
            const float p2 = __expf(v[tt][2] - nm);
            const float p3 = __expf(v[tt][3] - nm);
            srow += (p0 + p1) + (p2 + p3);
            uint2 pk;
            pk.x = cvtpk(p0, p1);
            pk.y = cvtpk(p2, p3);
            *(uint2*)&Pw[lx * PPAD + tt * 16 + qw * 4] = pk;
        }

        // ---- PV = mfma(FW, P): D[d][n] ----
#pragma unroll
        for (int ks = 0; ks < 2; ++ks) {
            const short8 ap = *(const short8*)&Pw[lx * PPAD + ks * 32 + qw * 8];
#pragma unroll
            for (int nb = 0; nb < 4; ++nb) {
                const unsigned short* fr = Fc + (nb * 16 + lx) * 64;
                short8 fb = *(const short8*)(fr + (((ks * 4 + qw) ^ lx7) * 8));
                acc[nb] = __builtin_amdgcn_mfma_f32_16x16x32_bf16(fb, ap, acc[nb], 0, 0, 0);
            }
        }

        __syncthreads();   // drains DMA for i+1; all waves done with cur
    }

    // ---- epilogue ----
    srow += __shfl_xor(srow, 16);
    srow += __shfl_xor(srow, 32);
    const float inv = 1.f / srow;
    float* Ow = (float*)smem + W * 16 * 68;
#pragma unroll
    for (int nb = 0; nb < 4; ++nb)
#pragma unroll
        for (int r = 0; r < 4; ++r)
            Ow[lx * 68 + nb * 16 + qw * 4 + r] = acc[nb][r] * inv;
    {
        const int row = lane >> 2, d0 = (lane & 3) * 16;
        const float* Orow = (float*)smem + W * 16 * 68 + row * 68;
        float* op = out + (size_t)(n0 + W * 16 + row) * 1024 + g * 64 + d0;
#pragma unroll
        for (int j = 0; j < 4; ++j) {
            float4 o = *(const float4*)(Orow + d0 + j * 4);
            const float4 b4 = *(const float4*)&bv[g * 64 + d0 + j * 4];
            o.x += b4.x; o.y += b4.y; o.z += b4.z; o.w += b4.w;
            *(float4*)(op + j * 4) = o;
        }
    }
#undef GLD
}

extern "C" void kernel_launch(void* const* d_in, const int* in_sizes, int n_in,
                              void* d_out, int out_size, void* d_ws, size_t ws_size,
                              hipStream_t stream)
{
    const float* feats = (const float*)d_in[0];
    const float* rois  = (const float*)d_in[1];
    const float* Wq    = (const float*)d_in[2];
    const float* bq    = (const float*)d_in[3];
    const float* Wk    = (const float*)d_in[4];
    const float* bk    = (const float*)d_in[5];
    const float* Wg    = (const float*)d_in[6];
    const float* bg    = (const float*)d_in[7];
    const float* Wv    = (const float*)d_in[8];
    const float* bv    = (const float*)d_in[9];
    float* out = (float*)d_out;

    char* wsb = (char*)d_ws;
    unsigned short* logwb  = (unsigned short*)(wsb + (0ull  << 20));  // 32MB
    unsigned short* featsb = (unsigned short*)(wsb + (64ull << 20));
    unsigned short* qb     = (unsigned short*)(wsb + (66ull << 20));
    unsigned short* kb     = (unsigned short*)(wsb + (68ull << 20));
    unsigned short* FWtb   = (unsigned short*)(wsb + (70ull << 20));
    unsigned short* Wqb    = (unsigned short*)(wsb + (80ull << 20));
    unsigned short* Wkb    = (unsigned short*)(wsb + (82ull << 20));
    unsigned short* Wvb    = (unsigned short*)(wsb + (84ull << 20));

    cvt_kernel<<<dim3(512, 4), 256, 0, stream>>>(feats, Wq, Wk, Wv,
                                                 featsb, Wqb, Wkb, Wvb);

    Triples tr;
    tr.A[0] = featsb; tr.B[0] = Wqb;    tr.C[0] = qb;   tr.bias[0] = bq;
    tr.A[1] = featsb; tr.B[1] = Wkb;    tr.C[1] = kb;   tr.bias[1] = bk;
    tr.A[2] = Wvb;    tr.B[2] = featsb; tr.C[2] = FWtb; tr.bias[2] = nullptr;
    prep_kernel<<<1216, 256, 0, stream>>>(tr, rois, Wg, bg, logwb);

    attn_kernel<<<256, 256, 0, stream>>>(qb, kb, logwb, FWtb, bv, out);
}